// Round 11
// baseline (1476.829 us; speedup 1.0000x reference)
//
#include <hip/hip_runtime.h>
#include <hip/hip_bf16.h>
#include <math.h>

#define NN 100000
#define NE 1600000
#define BSHIFT 9
#define NBUCK ((NN + (1 << BSHIFT) - 1) >> BSHIFT)   // 196
#define CAP 10240                                    // max edges/bucket (~8163+3.5sigma ~ 8480)
#define HROWS 128

// ============ GEMM1: x[N,128] @ W1[128,64] -> out_bf16[N,64] ============
// 64-row tile, thread = 4 rows x 4 interleaved cols; K-half-1 register-prefetched.
__global__ __launch_bounds__(256, 3) void gemm1_tile(const float* __restrict__ x,
                                                     const float* __restrict__ W,
                                                     __hip_bfloat16* __restrict__ out) {
    __shared__ float Wt[64 * 132];     // 33792 B
    __shared__ float Xs[64 * 68];      // 17408 B
    const int tid = threadIdx.x;
    const int row0 = blockIdx.x * 64;
    for (int i = tid; i < 64 * 128; i += 256) {
        const int c = i >> 7, k = i & 127;
        Wt[c * 132 + k] = W[k * 64 + c];
    }
    // stage K-half 0 into LDS
#pragma unroll
    for (int n = 0; n < 4; ++n) {
        const int i = tid + n * 256;
        const int r = i >> 4, kq = i & 15;
        const int row = row0 + r;
        float4 v = make_float4(0.f, 0.f, 0.f, 0.f);
        if (row < NN) v = *(const float4*)(x + (size_t)row * 128 + kq * 4);
        *(float4*)(&Xs[r * 68 + kq * 4]) = v;
    }
    // prefetch K-half 1 into registers (overlaps half-0 compute)
    float4 pf[4];
#pragma unroll
    for (int n = 0; n < 4; ++n) {
        const int i = tid + n * 256;
        const int r = i >> 4, kq = i & 15;
        const int row = row0 + r;
        pf[n] = make_float4(0.f, 0.f, 0.f, 0.f);
        if (row < NN) pf[n] = *(const float4*)(x + (size_t)row * 128 + 64 + kq * 4);
    }
    const int tc = tid & 15;
    const int tr = tid >> 4;
    float acc[4][4] = {};
    const float* wb = &Wt[tc * 132];
    const float* xb = &Xs[(tr * 4) * 68];
    __syncthreads();
    // ---- compute half 0 ----
#pragma unroll 2
    for (int k = 0; k < 64; k += 4) {
        float4 xv[4], wv[4];
#pragma unroll
        for (int r = 0; r < 4; ++r) xv[r] = *(const float4*)(xb + r * 68 + k);
#pragma unroll
        for (int c = 0; c < 4; ++c) wv[c] = *(const float4*)(wb + c * (16 * 132) + k);
#pragma unroll
        for (int r = 0; r < 4; ++r)
#pragma unroll
            for (int c = 0; c < 4; ++c) {
                acc[r][c] = fmaf(xv[r].x, wv[c].x, acc[r][c]);
                acc[r][c] = fmaf(xv[r].y, wv[c].y, acc[r][c]);
                acc[r][c] = fmaf(xv[r].z, wv[c].z, acc[r][c]);
                acc[r][c] = fmaf(xv[r].w, wv[c].w, acc[r][c]);
            }
    }
    __syncthreads();
#pragma unroll
    for (int n = 0; n < 4; ++n) {
        const int i = tid + n * 256;
        const int r = i >> 4, kq = i & 15;
        *(float4*)(&Xs[r * 68 + kq * 4]) = pf[n];
    }
    __syncthreads();
    // ---- compute half 1 ----
#pragma unroll 2
    for (int k = 0; k < 64; k += 4) {
        float4 xv[4], wv[4];
#pragma unroll
        for (int r = 0; r < 4; ++r) xv[r] = *(const float4*)(xb + r * 68 + k);
#pragma unroll
        for (int c = 0; c < 4; ++c) wv[c] = *(const float4*)(wb + c * (16 * 132) + 64 + k);
#pragma unroll
        for (int r = 0; r < 4; ++r)
#pragma unroll
            for (int c = 0; c < 4; ++c) {
                acc[r][c] = fmaf(xv[r].x, wv[c].x, acc[r][c]);
                acc[r][c] = fmaf(xv[r].y, wv[c].y, acc[r][c]);
                acc[r][c] = fmaf(xv[r].z, wv[c].z, acc[r][c]);
                acc[r][c] = fmaf(xv[r].w, wv[c].w, acc[r][c]);
            }
    }
#pragma unroll
    for (int r = 0; r < 4; ++r) {
        const int row = row0 + tr * 4 + r;
        if (row < NN) {
#pragma unroll
            for (int c = 0; c < 4; ++c)
                out[(size_t)row * 64 + tc + c * 16] = __float2bfloat16(acc[r][c]);
        }
    }
}

// ============ GEMM2: h[N,64] @ W2[64,64] -> out_bf16[N,64] ============
__global__ __launch_bounds__(256, 3) void gemm2_tile(const float* __restrict__ h,
                                                     const float* __restrict__ W,
                                                     __hip_bfloat16* __restrict__ out) {
    __shared__ float Wt[64 * 68];
    __shared__ float Xs[64 * 68];
    const int tid = threadIdx.x;
    const int row0 = blockIdx.x * 64;
    for (int i = tid; i < 64 * 64; i += 256) {
        const int c = i >> 6, k = i & 63;
        Wt[c * 68 + k] = W[k * 64 + c];
    }
    for (int i = tid; i < 64 * 16; i += 256) {
        const int r = i >> 4, kq = i & 15;
        const int row = row0 + r;
        float4 v = make_float4(0.f, 0.f, 0.f, 0.f);
        if (row < NN) v = *(const float4*)(h + (size_t)row * 64 + kq * 4);
        *(float4*)(&Xs[r * 68 + kq * 4]) = v;
    }
    __syncthreads();
    const int tc = tid & 15;
    const int tr = tid >> 4;
    float acc[4][4] = {};
    const float* xb = &Xs[(tr * 4) * 68];
    const float* wb = &Wt[tc * 68];
#pragma unroll 2
    for (int k = 0; k < 64; k += 4) {
        float4 xv[4], wv[4];
#pragma unroll
        for (int r = 0; r < 4; ++r) xv[r] = *(const float4*)(xb + r * 68 + k);
#pragma unroll
        for (int c = 0; c < 4; ++c) wv[c] = *(const float4*)(wb + c * (16 * 68) + k);
#pragma unroll
        for (int r = 0; r < 4; ++r)
#pragma unroll
            for (int c = 0; c < 4; ++c) {
                acc[r][c] = fmaf(xv[r].x, wv[c].x, acc[r][c]);
                acc[r][c] = fmaf(xv[r].y, wv[c].y, acc[r][c]);
                acc[r][c] = fmaf(xv[r].z, wv[c].z, acc[r][c]);
                acc[r][c] = fmaf(xv[r].w, wv[c].w, acc[r][c]);
            }
    }
#pragma unroll
    for (int r = 0; r < 4; ++r) {
        const int row = row0 + tr * 4 + r;
        if (row < NN) {
#pragma unroll
            for (int c = 0; c < 4; ++c)
                out[(size_t)row * 64 + tc + c * 16] = __float2bfloat16(acc[r][c]);
        }
    }
}

// ---------------- init fixed-capacity bucket cursors ----------------
__global__ void init_bcur(int* __restrict__ bcur) {
    const int t = threadIdx.x;
    if (t < NBUCK) bcur[t] = t * CAP;
}

// ---------------- bin edges into fixed-capacity 512-node buckets ----------------
// packed payload: {src | (dloc<<17), w_f32}
__global__ __launch_bounds__(512) void bin_edges(const int* __restrict__ es,
                                                 const int* __restrict__ ed,
                                                 const float* __restrict__ ew,
                                                 int* __restrict__ bcur,
                                                 int2* __restrict__ srcdw) {
    __shared__ int hist[NBUCK];
    __shared__ int base[NBUCK];
    const int tid = threadIdx.x;
    const int e0 = blockIdx.x * 4096;
    for (int i = tid; i < NBUCK; i += 512) hist[i] = 0;
    __syncthreads();
    int d[8];
#pragma unroll
    for (int j = 0; j < 8; ++j) {
        const int e = e0 + j * 512 + tid;
        d[j] = (e < NE) ? ed[e] : -1;
        if (d[j] >= 0) atomicAdd(&hist[d[j] >> BSHIFT], 1);
    }
    __syncthreads();
    for (int i = tid; i < NBUCK; i += 512) base[i] = atomicAdd(&bcur[i], hist[i]);
    __syncthreads();
    for (int i = tid; i < NBUCK; i += 512) hist[i] = 0;
    __syncthreads();
#pragma unroll
    for (int j = 0; j < 8; ++j) {
        const int e = e0 + j * 512 + tid;
        if (d[j] >= 0) {
            const int bb = d[j] >> BSHIFT;
            const int l = atomicAdd(&hist[bb], 1);
            const int p = base[bb] + l;
            srcdw[p] = make_int2(es[e] | ((d[j] & 511) << 17), __float_as_int(ew[e]));
        }
    }
}

// ---------------- bucket SpMM: LDS accumulation, no edge sort needed ----------------
// grid = NBUCK*4; block handles one bucket x 16-feature quarter.
// wave: pe = lane>>3 (8 edges), f2 = lane&7 (8 bf16 pairs = 16 feats).
__global__ __launch_bounds__(256) void spmm_bucket(const __hip_bfloat16* __restrict__ feat,
                                                   const int2* __restrict__ srcdw,
                                                   const int* __restrict__ bcur,
                                                   const float* __restrict__ bias,
                                                   float* __restrict__ out) {
    __shared__ float acc[512 * 17];    // 34816 B, pad 17 to spread banks
    const int tid = threadIdx.x;
    const int b = blockIdx.x >> 2;
    const int q = blockIdx.x & 3;
    for (int i = tid; i < 512 * 17; i += 256) acc[i] = 0.f;
    const int beg = b * CAP;
    const int end = bcur[b];
    const int lane = tid & 63;
    const int wv = tid >> 6;
    const int pe = lane >> 3;
    const int f2 = lane & 7;
    const __hip_bfloat16* fq = feat + q * 16 + f2 * 2;
    __syncthreads();
    for (int i = beg + wv * 8; i < end; i += 128) {
#pragma unroll
        for (int j = 0; j < 4; ++j) {
            const int idx = i + j * 32 + pe;
            const int2 e = srcdw[idx];                       // in-bounds by CAP margin
            const float w = (idx < end) ? __int_as_float(e.y) : 0.f;
            const int src = e.x & 0x1FFFF;
            const int dl = (e.x >> 17) & 0x1FF;
            const unsigned g = *(const unsigned*)(fq + (size_t)src * 64);
            atomicAdd(&acc[dl * 17 + f2 * 2],     __uint_as_float(g << 16) * w);
            atomicAdd(&acc[dl * 17 + f2 * 2 + 1], __uint_as_float(g & 0xffff0000u) * w);
        }
    }
    __syncthreads();
    // epilogue: bias + relu, one 64B line per node
    const float* bq = bias + q * 16;
    float bv[16];
#pragma unroll
    for (int c = 0; c < 16; ++c) bv[c] = bq[c];
#pragma unroll
    for (int rr = 0; rr < 2; ++rr) {
        const int row = tid * 2 + rr;
        const int node = (b << 9) + row;
        if (node < NN) {
            float* op = out + (size_t)node * 64 + q * 16;
#pragma unroll
            for (int c = 0; c < 16; c += 4) {
                float4 o;
                o.x = fmaxf(acc[row * 17 + c]     + bv[c],     0.f);
                o.y = fmaxf(acc[row * 17 + c + 1] + bv[c + 1], 0.f);
                o.z = fmaxf(acc[row * 17 + c + 2] + bv[c + 2], 0.f);
                o.w = fmaxf(acc[row * 17 + c + 3] + bv[c + 3], 0.f);
                *(float4*)(op + c) = o;
            }
        }
    }
}

// ============ head: 128 rows x 40 cols per block, register-tiled ============
__global__ __launch_bounds__(256) void head_tile(const float* __restrict__ h2,
                                                 const float* __restrict__ Wl,
                                                 const float* __restrict__ bl,
                                                 float* __restrict__ logits,
                                                 float* __restrict__ logp) {
    __shared__ float Wt[40 * 68];      // 10880 B
    __shared__ float Xs[HROWS * 68];   // 34816 B
    __shared__ float bs[40];
    const int tid = threadIdx.x;
    const int row0 = blockIdx.x * HROWS;
    for (int i = tid; i < 64 * 40; i += 256) {
        const int k = i / 40, c = i - k * 40;
        Wt[c * 68 + k] = Wl[i];
    }
    if (tid < 40) bs[tid] = bl[tid];
    for (int i = tid; i < HROWS * 16; i += 256) {
        const int r = i >> 4, kq = i & 15;
        const int row = row0 + r;
        float4 v = make_float4(0.f, 0.f, 0.f, 0.f);
        if (row < NN) v = *(const float4*)(h2 + (size_t)row * 64 + kq * 4);
        *(float4*)(&Xs[r * 68 + kq * 4]) = v;
    }
    __syncthreads();
    const int tcol = tid & 3;
    const int trow = tid >> 2;
    float acc[2][10] = {};
    const float* xb0 = &Xs[trow * 68];
    const float* xb1 = &Xs[(trow + 64) * 68];
    const float* wb = &Wt[(tcol * 10) * 68];
    for (int k = 0; k < 64; k += 4) {
        const float4 x0 = *(const float4*)(xb0 + k);
        const float4 x1 = *(const float4*)(xb1 + k);
#pragma unroll
        for (int c = 0; c < 10; ++c) {
            const float4 wv = *(const float4*)(wb + c * 68 + k);
            acc[0][c] = fmaf(x0.x, wv.x, acc[0][c]);
            acc[0][c] = fmaf(x0.y, wv.y, acc[0][c]);
            acc[0][c] = fmaf(x0.z, wv.z, acc[0][c]);
            acc[0][c] = fmaf(x0.w, wv.w, acc[0][c]);
            acc[1][c] = fmaf(x1.x, wv.x, acc[1][c]);
            acc[1][c] = fmaf(x1.y, wv.y, acc[1][c]);
            acc[1][c] = fmaf(x1.z, wv.z, acc[1][c]);
            acc[1][c] = fmaf(x1.w, wv.w, acc[1][c]);
        }
    }
    float bv[10];
#pragma unroll
    for (int c = 0; c < 10; ++c) bv[c] = bs[tcol * 10 + c];
#pragma unroll
    for (int r = 0; r < 2; ++r) {
        const int row = row0 + trow + r * 64;
#pragma unroll
        for (int c = 0; c < 10; ++c) acc[r][c] += bv[c];
        float m = acc[r][0];
#pragma unroll
        for (int c = 1; c < 10; ++c) m = fmaxf(m, acc[r][c]);
        m = fmaxf(m, __shfl_xor(m, 1, 64));
        m = fmaxf(m, __shfl_xor(m, 2, 64));
        float s = 0.f;
#pragma unroll
        for (int c = 0; c < 10; ++c) s += expf(acc[r][c] - m);
        s += __shfl_xor(s, 1, 64);
        s += __shfl_xor(s, 2, 64);
        const float lse = logf(s) + m;
        if (row < NN) {
            float* lg = logits + (size_t)row * 40 + tcol * 10;
            float* lp = logp   + (size_t)row * 40 + tcol * 10;
#pragma unroll
            for (int c = 0; c < 10; c += 2) {
                *(float2*)(lg + c) = make_float2(acc[r][c], acc[r][c + 1]);
                *(float2*)(lp + c) = make_float2(acc[r][c] - lse, acc[r][c + 1] - lse);
            }
        }
    }
}

extern "C" void kernel_launch(void* const* d_in, const int* in_sizes, int n_in,
                              void* d_out, int out_size, void* d_ws, size_t ws_size,
                              hipStream_t stream) {
    const float* x  = (const float*)d_in[0];
    const int*   es = (const int*)  d_in[1];
    const int*   ed = (const int*)  d_in[2];
    const float* ew = (const float*)d_in[3];
    const float* W1 = (const float*)d_in[4];
    const float* b1 = (const float*)d_in[5];
    const float* W2 = (const float*)d_in[6];
    const float* b2 = (const float*)d_in[7];
    const float* Wl = (const float*)d_in[8];
    const float* bl = (const float*)d_in[9];

    float* out    = (float*)d_out;
    float* logp   = out;                          // [N,40]
    float* h1     = logp + (size_t)NN * 40;       // [N,64]
    float* h2     = h1   + (size_t)NN * 64;       // [N,64]
    float* logits = h2   + (size_t)NN * 64;       // [N,40]

    // workspace layout (srcdw must NOT overlay ws0 — both live across both layers)
    char* wsb = (char*)d_ws;
    __hip_bfloat16* ws0 = (__hip_bfloat16*)wsb;                       // [N,64] bf16 12.8 MB
    int2* srcdw = (int2*)(wsb + (size_t)NN * 64 * 2);                 // [NBUCK*CAP] 16.06 MB
    int*  bcur  = (int*)((char*)srcdw + (size_t)NBUCK * CAP * 8);     // [NBUCK]

    const int gemmGrid = (NN + 63) / 64;
    const int binGrid  = (NE + 4095) / 4096;      // 391

    // ---- build bucket-grouped edge list (single pass, fixed capacity) ----
    init_bcur<<<1, 256, 0, stream>>>(bcur);
    bin_edges<<<binGrid, 512, 0, stream>>>(es, ed, ew, bcur, srcdw);

    // ---- layer 1 ----
    gemm1_tile<<<gemmGrid, 256, 0, stream>>>(x, W1, ws0);
    spmm_bucket<<<NBUCK * 4, 256, 0, stream>>>(ws0, srcdw, bcur, b1, h1);

    // ---- layer 2 ----
    gemm2_tile<<<gemmGrid, 256, 0, stream>>>(h1, W2, ws0);
    spmm_bucket<<<NBUCK * 4, 256, 0, stream>>>(ws0, srcdw, bcur, b2, h2);

    // ---- head ----
    head_tile<<<(NN + HROWS - 1) / HROWS, 256, 0, stream>>>(h2, Wl, bl, logits, logp);
}

// Round 12
// 255.061 us; speedup vs baseline: 5.7901x; 5.7901x over previous
//
#include <hip/hip_runtime.h>
#include <hip/hip_bf16.h>
#include <math.h>

#define NN 100000
#define NE 1600000
#define BSHIFT 9
#define NBUCK ((NN + (1 << BSHIFT) - 1) >> BSHIFT)   // 196
#define CAP 10240                                    // max edges/bucket (mean 8192, sigma ~90)
#define BINB 512
#define BCHUNK 3072
#define BINGRID ((NE + BCHUNK - 1) / BCHUNK)         // 521
#define HROWS 128

// ============ GEMM1: x[N,128] @ W1[128,64] -> out_bf16[N,64] ============
// 64-row tile, thread = 4 rows x 4 interleaved cols; W^T staged per K-half
// so LDS = 34.8 KB -> 4 blocks/CU (was 50 KB / 3 blocks).
__global__ __launch_bounds__(256, 4) void gemm1_tile(const float* __restrict__ x,
                                                     const float* __restrict__ W,
                                                     __hip_bfloat16* __restrict__ out) {
    __shared__ float Wt[64 * 68];      // 17408 B (one K-half of W^T)
    __shared__ float Xs[64 * 68];      // 17408 B
    const int tid = threadIdx.x;
    const int row0 = blockIdx.x * 64;
    const int tc = tid & 15;
    const int tr = tid >> 4;
    float acc[4][4] = {};
    const float* xb = &Xs[(tr * 4) * 68];
    const float* wb = &Wt[tc * 68];
    for (int kh = 0; kh < 2; ++kh) {
        if (kh) __syncthreads();       // previous half's readers done
        // stage W^T half: lanes walk k -> stride-1 LDS writes; W is L2-hot
        for (int i = tid; i < 64 * 64; i += 256) {
            const int c = i >> 6, k = i & 63;
            Wt[c * 68 + k] = W[(kh * 64 + k) * 64 + c];
        }
        // stage X half
        for (int i = tid; i < 64 * 16; i += 256) {
            const int r = i >> 4, kq = i & 15;
            const int row = row0 + r;
            float4 v = make_float4(0.f, 0.f, 0.f, 0.f);
            if (row < NN) v = *(const float4*)(x + (size_t)row * 128 + kh * 64 + kq * 4);
            *(float4*)(&Xs[r * 68 + kq * 4]) = v;
        }
        __syncthreads();
#pragma unroll 2
        for (int k = 0; k < 64; k += 4) {
            float4 xv[4], wv[4];
#pragma unroll
            for (int r = 0; r < 4; ++r) xv[r] = *(const float4*)(xb + r * 68 + k);
#pragma unroll
            for (int c = 0; c < 4; ++c) wv[c] = *(const float4*)(wb + c * (16 * 68) + k);
#pragma unroll
            for (int r = 0; r < 4; ++r)
#pragma unroll
                for (int c = 0; c < 4; ++c) {
                    acc[r][c] = fmaf(xv[r].x, wv[c].x, acc[r][c]);
                    acc[r][c] = fmaf(xv[r].y, wv[c].y, acc[r][c]);
                    acc[r][c] = fmaf(xv[r].z, wv[c].z, acc[r][c]);
                    acc[r][c] = fmaf(xv[r].w, wv[c].w, acc[r][c]);
                }
        }
    }
#pragma unroll
    for (int r = 0; r < 4; ++r) {
        const int row = row0 + tr * 4 + r;
        if (row < NN) {
#pragma unroll
            for (int c = 0; c < 4; ++c)
                out[(size_t)row * 64 + tc + c * 16] = __float2bfloat16(acc[r][c]);
        }
    }
}

// ============ GEMM2: h[N,64] @ W2[64,64] -> out_bf16[N,64] ============
__global__ __launch_bounds__(256, 4) void gemm2_tile(const float* __restrict__ h,
                                                     const float* __restrict__ W,
                                                     __hip_bfloat16* __restrict__ out) {
    __shared__ float Wt[64 * 68];
    __shared__ float Xs[64 * 68];
    const int tid = threadIdx.x;
    const int row0 = blockIdx.x * 64;
    for (int i = tid; i < 64 * 64; i += 256) {
        const int c = i >> 6, k = i & 63;
        Wt[c * 68 + k] = W[k * 64 + c];
    }
    for (int i = tid; i < 64 * 16; i += 256) {
        const int r = i >> 4, kq = i & 15;
        const int row = row0 + r;
        float4 v = make_float4(0.f, 0.f, 0.f, 0.f);
        if (row < NN) v = *(const float4*)(h + (size_t)row * 64 + kq * 4);
        *(float4*)(&Xs[r * 68 + kq * 4]) = v;
    }
    __syncthreads();
    const int tc = tid & 15;
    const int tr = tid >> 4;
    float acc[4][4] = {};
    const float* xb = &Xs[(tr * 4) * 68];
    const float* wb = &Wt[tc * 68];
#pragma unroll 2
    for (int k = 0; k < 64; k += 4) {
        float4 xv[4], wv[4];
#pragma unroll
        for (int r = 0; r < 4; ++r) xv[r] = *(const float4*)(xb + r * 68 + k);
#pragma unroll
        for (int c = 0; c < 4; ++c) wv[c] = *(const float4*)(wb + c * (16 * 68) + k);
#pragma unroll
        for (int r = 0; r < 4; ++r)
#pragma unroll
            for (int c = 0; c < 4; ++c) {
                acc[r][c] = fmaf(xv[r].x, wv[c].x, acc[r][c]);
                acc[r][c] = fmaf(xv[r].y, wv[c].y, acc[r][c]);
                acc[r][c] = fmaf(xv[r].z, wv[c].z, acc[r][c]);
                acc[r][c] = fmaf(xv[r].w, wv[c].w, acc[r][c]);
            }
    }
#pragma unroll
    for (int r = 0; r < 4; ++r) {
        const int row = row0 + tr * 4 + r;
        if (row < NN) {
#pragma unroll
            for (int c = 0; c < 4; ++c)
                out[(size_t)row * 64 + tc + c * 16] = __float2bfloat16(acc[r][c]);
        }
    }
}

// ---------------- init fixed-capacity bucket cursors ----------------
__global__ void init_bcur(int* __restrict__ bcur) {
    const int t = threadIdx.x;
    if (t < NBUCK) bcur[t] = t * CAP;
}

// ---------------- bin edges into fixed-capacity buckets (packed payload) ----------------
// payload: {src | (dloc<<17), w_f32}; 512 threads, 3072-edge chunks -> ~50% occupancy
__global__ __launch_bounds__(BINB) void bin_edges(const int* __restrict__ es,
                                                  const int* __restrict__ ed,
                                                  const float* __restrict__ ew,
                                                  int* __restrict__ bcur,
                                                  int2* __restrict__ srcdw) {
    __shared__ int hist[NBUCK];
    __shared__ int base[NBUCK];
    const int tid = threadIdx.x;
    const int e0 = blockIdx.x * BCHUNK;
    for (int i = tid; i < NBUCK; i += BINB) hist[i] = 0;
    __syncthreads();
    int d[6];
#pragma unroll
    for (int j = 0; j < 6; ++j) {
        const int e = e0 + j * BINB + tid;
        d[j] = (e < NE) ? ed[e] : -1;
        if (d[j] >= 0) atomicAdd(&hist[d[j] >> BSHIFT], 1);
    }
    __syncthreads();
    for (int i = tid; i < NBUCK; i += BINB) base[i] = atomicAdd(&bcur[i], hist[i]);
    __syncthreads();
    for (int i = tid; i < NBUCK; i += BINB) hist[i] = 0;
    __syncthreads();
#pragma unroll
    for (int j = 0; j < 6; ++j) {
        const int e = e0 + j * BINB + tid;
        if (d[j] >= 0) {
            const int bb = d[j] >> BSHIFT;
            const int l = atomicAdd(&hist[bb], 1);
            const int p = base[bb] + l;
            srcdw[p] = make_int2(es[e] | ((d[j] & 511) << 17), __float_as_int(ew[e]));
        }
    }
}

// ---------------- per-bucket CSR finalize: LDS hist + scan + place ----------------
// one block per bucket; emits rng[node]={beg,end} and dest-sorted edges2 in the
// bucket's fixed-capacity window. No global atomics.
__global__ __launch_bounds__(512) void bucket_csr(const int2* __restrict__ srcdw,
                                                  const int* __restrict__ bcur,
                                                  int2* __restrict__ rng,
                                                  int2* __restrict__ edges2) {
    __shared__ int A[512], B[512];
    const int tid = threadIdx.x;
    const int b = blockIdx.x;
    const int base = b * CAP;
    const int cnt = bcur[b] - base;
    A[tid] = 0;
    __syncthreads();
    for (int e = tid; e < cnt; e += 512)
        atomicAdd(&A[(srcdw[base + e].x >> 17) & 511], 1);
    __syncthreads();
    const int v = A[tid];
    int* src = A;
    int* dst = B;
    for (int d = 1; d < 512; d <<= 1) {
        dst[tid] = src[tid] + ((tid >= d) ? src[tid - d] : 0);
        __syncthreads();
        int* t = src; src = dst; dst = t;
    }
    const int incl = src[tid];
    const int excl = incl - v;
    const int node = (b << BSHIFT) + tid;
    if (node < NN) rng[node] = make_int2(base + excl, base + incl);
    dst[tid] = excl;                   // cursors
    __syncthreads();
    for (int e = tid; e < cnt; e += 512) {
        const int2 sw = srcdw[base + e];
        const int dl = (sw.x >> 17) & 511;
        const int pos = atomicAdd(&dst[dl], 1);
        edges2[base + pos] = make_int2(sw.x & 0x1FFFF, sw.y);
    }
}

// ---------------- CSR SpMM (bf16 gather, 2 edges/instr) + bias + relu ----------------
__global__ __launch_bounds__(256) void spmm_csr(const __hip_bfloat16* __restrict__ feat,
                                                const int2* __restrict__ rng,
                                                const int2* __restrict__ edges2,
                                                const float* __restrict__ b,
                                                float* __restrict__ out) {
    const int w = threadIdx.x >> 6;
    const int lane = threadIdx.x & 63;
    const int n = blockIdx.x * 4 + w;
    const int2 r = rng[n];
    const int beg = r.x;
    const int end = r.y;
    const int p = lane >> 5;
    const int f2 = lane & 31;
    float ax = 0.f, ay = 0.f;
    int i = beg;
    for (; i + 7 < end; i += 8) {
        const int2 e0 = edges2[i     + p];
        const int2 e1 = edges2[i + 2 + p];
        const int2 e2 = edges2[i + 4 + p];
        const int2 e3 = edges2[i + 6 + p];
        const unsigned g0 = *(const unsigned*)(feat + (size_t)e0.x * 64 + f2 * 2);
        const unsigned g1 = *(const unsigned*)(feat + (size_t)e1.x * 64 + f2 * 2);
        const unsigned g2 = *(const unsigned*)(feat + (size_t)e2.x * 64 + f2 * 2);
        const unsigned g3 = *(const unsigned*)(feat + (size_t)e3.x * 64 + f2 * 2);
        const float w0 = __int_as_float(e0.y), w1 = __int_as_float(e1.y);
        const float w2 = __int_as_float(e2.y), w3 = __int_as_float(e3.y);
        ax = fmaf(__uint_as_float(g0 << 16), w0, ax);
        ay = fmaf(__uint_as_float(g0 & 0xffff0000u), w0, ay);
        ax = fmaf(__uint_as_float(g1 << 16), w1, ax);
        ay = fmaf(__uint_as_float(g1 & 0xffff0000u), w1, ay);
        ax = fmaf(__uint_as_float(g2 << 16), w2, ax);
        ay = fmaf(__uint_as_float(g2 & 0xffff0000u), w2, ay);
        ax = fmaf(__uint_as_float(g3 << 16), w3, ax);
        ay = fmaf(__uint_as_float(g3 & 0xffff0000u), w3, ay);
    }
    for (; i + 1 < end; i += 2) {
        const int2 e = edges2[i + p];
        const unsigned g = *(const unsigned*)(feat + (size_t)e.x * 64 + f2 * 2);
        const float wv = __int_as_float(e.y);
        ax = fmaf(__uint_as_float(g << 16), wv, ax);
        ay = fmaf(__uint_as_float(g & 0xffff0000u), wv, ay);
    }
    if (i < end && p == 0) {
        const int2 e = edges2[i];
        const unsigned g = *(const unsigned*)(feat + (size_t)e.x * 64 + f2 * 2);
        const float wv = __int_as_float(e.y);
        ax = fmaf(__uint_as_float(g << 16), wv, ax);
        ay = fmaf(__uint_as_float(g & 0xffff0000u), wv, ay);
    }
    ax += __shfl_xor(ax, 32, 64);
    ay += __shfl_xor(ay, 32, 64);
    if (p == 0) {
        float vx = ax + b[f2 * 2];
        float vy = ay + b[f2 * 2 + 1];
        vx = vx > 0.f ? vx : 0.f;
        vy = vy > 0.f ? vy : 0.f;
        *(float2*)(out + (size_t)n * 64 + f2 * 2) = make_float2(vx, vy);
    }
}

// ============ head: 128 rows x 40 cols per block, register-tiled ============
__global__ __launch_bounds__(256) void head_tile(const float* __restrict__ h2,
                                                 const float* __restrict__ Wl,
                                                 const float* __restrict__ bl,
                                                 float* __restrict__ logits,
                                                 float* __restrict__ logp) {
    __shared__ float Wt[40 * 68];      // 10880 B
    __shared__ float Xs[HROWS * 68];   // 34816 B
    __shared__ float bs[40];
    const int tid = threadIdx.x;
    const int row0 = blockIdx.x * HROWS;
    for (int i = tid; i < 64 * 40; i += 256) {
        const int k = i / 40, c = i - k * 40;
        Wt[c * 68 + k] = Wl[i];
    }
    if (tid < 40) bs[tid] = bl[tid];
    for (int i = tid; i < HROWS * 16; i += 256) {
        const int r = i >> 4, kq = i & 15;
        const int row = row0 + r;
        float4 v = make_float4(0.f, 0.f, 0.f, 0.f);
        if (row < NN) v = *(const float4*)(h2 + (size_t)row * 64 + kq * 4);
        *(float4*)(&Xs[r * 68 + kq * 4]) = v;
    }
    __syncthreads();
    const int tcol = tid & 3;
    const int trow = tid >> 2;
    float acc[2][10] = {};
    const float* xb0 = &Xs[trow * 68];
    const float* xb1 = &Xs[(trow + 64) * 68];
    const float* wb = &Wt[(tcol * 10) * 68];
    for (int k = 0; k < 64; k += 4) {
        const float4 x0 = *(const float4*)(xb0 + k);
        const float4 x1 = *(const float4*)(xb1 + k);
#pragma unroll
        for (int c = 0; c < 10; ++c) {
            const float4 wv = *(const float4*)(wb + c * 68 + k);
            acc[0][c] = fmaf(x0.x, wv.x, acc[0][c]);
            acc[0][c] = fmaf(x0.y, wv.y, acc[0][c]);
            acc[0][c] = fmaf(x0.z, wv.z, acc[0][c]);
            acc[0][c] = fmaf(x0.w, wv.w, acc[0][c]);
            acc[1][c] = fmaf(x1.x, wv.x, acc[1][c]);
            acc[1][c] = fmaf(x1.y, wv.y, acc[1][c]);
            acc[1][c] = fmaf(x1.z, wv.z, acc[1][c]);
            acc[1][c] = fmaf(x1.w, wv.w, acc[1][c]);
        }
    }
    float bv[10];
#pragma unroll
    for (int c = 0; c < 10; ++c) bv[c] = bs[tcol * 10 + c];
#pragma unroll
    for (int r = 0; r < 2; ++r) {
        const int row = row0 + trow + r * 64;
#pragma unroll
        for (int c = 0; c < 10; ++c) acc[r][c] += bv[c];
        float m = acc[r][0];
#pragma unroll
        for (int c = 1; c < 10; ++c) m = fmaxf(m, acc[r][c]);
        m = fmaxf(m, __shfl_xor(m, 1, 64));
        m = fmaxf(m, __shfl_xor(m, 2, 64));
        float s = 0.f;
#pragma unroll
        for (int c = 0; c < 10; ++c) s += expf(acc[r][c] - m);
        s += __shfl_xor(s, 1, 64);
        s += __shfl_xor(s, 2, 64);
        const float lse = logf(s) + m;
        if (row < NN) {
            float* lg = logits + (size_t)row * 40 + tcol * 10;
            float* lp = logp   + (size_t)row * 40 + tcol * 10;
#pragma unroll
            for (int c = 0; c < 10; c += 2) {
                *(float2*)(lg + c) = make_float2(acc[r][c], acc[r][c + 1]);
                *(float2*)(lp + c) = make_float2(acc[r][c] - lse, acc[r][c + 1] - lse);
            }
        }
    }
}

extern "C" void kernel_launch(void* const* d_in, const int* in_sizes, int n_in,
                              void* d_out, int out_size, void* d_ws, size_t ws_size,
                              hipStream_t stream) {
    const float* x  = (const float*)d_in[0];
    const int*   es = (const int*)  d_in[1];
    const int*   ed = (const int*)  d_in[2];
    const float* ew = (const float*)d_in[3];
    const float* W1 = (const float*)d_in[4];
    const float* b1 = (const float*)d_in[5];
    const float* W2 = (const float*)d_in[6];
    const float* b2 = (const float*)d_in[7];
    const float* Wl = (const float*)d_in[8];
    const float* bl = (const float*)d_in[9];

    float* out    = (float*)d_out;
    float* logp   = out;                          // [N,40]
    float* h1     = logp + (size_t)NN * 40;       // [N,64]
    float* h2     = h1   + (size_t)NN * 64;       // [N,64]
    float* logits = h2   + (size_t)NN * 64;       // [N,40]

    // workspace layout: srcdw (binned, dead after bucket_csr) overlays ws0 (GEMM out)
    char* wsb = (char*)d_ws;
    const size_t regionA = (size_t)NBUCK * CAP * 8;                   // 16.06 MB
    int2* srcdw = (int2*)wsb;                                         // [NBUCK*CAP]
    __hip_bfloat16* ws0 = (__hip_bfloat16*)wsb;                       // [N,64] bf16 (overlay)
    int2* edges2 = (int2*)(wsb + regionA);                            // [NBUCK*CAP] 16.06 MB
    int2* rng    = (int2*)((char*)edges2 + regionA);                  // [NN] 800 KB
    int*  bcur   = (int*)((char*)rng + (size_t)NN * 8);               // [NBUCK]

    const int gemmGrid = (NN + 63) / 64;

    // ---- build dest-sorted bucket-windowed CSR ----
    init_bcur<<<1, 256, 0, stream>>>(bcur);
    bin_edges<<<BINGRID, BINB, 0, stream>>>(es, ed, ew, bcur, srcdw);
    bucket_csr<<<NBUCK, 512, 0, stream>>>(srcdw, bcur, rng, edges2);

    // ---- layer 1 ----
    gemm1_tile<<<gemmGrid, 256, 0, stream>>>(x, W1, ws0);
    spmm_csr<<<NN / 4, 256, 0, stream>>>(ws0, rng, edges2, b1, h1);

    // ---- layer 2 ----
    gemm2_tile<<<gemmGrid, 256, 0, stream>>>(h1, W2, ws0);
    spmm_csr<<<NN / 4, 256, 0, stream>>>(ws0, rng, edges2, b2, h2);

    // ---- head ----
    head_tile<<<(NN + HROWS - 1) / HROWS, 256, 0, stream>>>(h2, Wl, bl, logits, logp);
}

// Round 13
// 216.176 us; speedup vs baseline: 6.8316x; 1.1799x over previous
//
#include <hip/hip_runtime.h>
#include <hip/hip_bf16.h>
#include <math.h>

#define NN 100000
#define NE 1600000
#define BSHIFT 9
#define NBUCK ((NN + (1 << BSHIFT) - 1) >> BSHIFT)   // 196
#define CAP 10240
#define BINB 512
#define BCHUNK 1536
#define BINGRID ((NE + BCHUNK - 1) / BCHUNK)         // 1042
#define HROWS 128

typedef __attribute__((ext_vector_type(8))) short bf16x8;
typedef __attribute__((ext_vector_type(4))) float f32x4;

static __device__ inline unsigned short f2b(float f) {
    __hip_bfloat16 b = __float2bfloat16(f);
    return *reinterpret_cast<unsigned short*>(&b);
}

// ============ GEMM1 (MFMA): x[N,128] @ W1[128,64] -> out_bf16[N,64] ============
// block = 128 rows, 4 waves; wave = 32 rows x 64 cols = 8 mfma tiles x 4 K-steps.
// LDS padded to 136 bf16/row (272 B -> 4-bank row stride, ~2-way on b128 reads).
__global__ __launch_bounds__(256) void gemm1_mfma(const float* __restrict__ x,
                                                  const float* __restrict__ W,
                                                  __hip_bfloat16* __restrict__ out) {
    __shared__ unsigned short Xs[128 * 136];   // 34816 B
    __shared__ unsigned short Wt[64 * 136];    // 17408 B  (Wt[n][k])
    const int tid = threadIdx.x;
    const int row0 = blockIdx.x * 128;
    // stage W^T as bf16 pairs: Wt[n][2kp..2kp+1] = W[2kp][n], W[2kp+1][n]
    for (int i = tid; i < 64 * 64; i += 256) {
        const int n = i & 63, kp = i >> 6;
        const unsigned pack = (unsigned)f2b(W[(2 * kp) * 64 + n]) |
                              ((unsigned)f2b(W[(2 * kp + 1) * 64 + n]) << 16);
        *(unsigned*)&Wt[n * 136 + 2 * kp] = pack;
    }
    // stage X rows as bf16 octets
    for (int i = tid; i < 128 * 16; i += 256) {
        const int r = i >> 4, q = i & 15;
        const int row = row0 + r;
        float v0 = 0.f, v1 = 0.f, v2 = 0.f, v3 = 0.f, v4 = 0.f, v5 = 0.f, v6 = 0.f, v7 = 0.f;
        if (row < NN) {
            const float4 a = *(const float4*)(x + (size_t)row * 128 + q * 8);
            const float4 b = *(const float4*)(x + (size_t)row * 128 + q * 8 + 4);
            v0 = a.x; v1 = a.y; v2 = a.z; v3 = a.w; v4 = b.x; v5 = b.y; v6 = b.z; v7 = b.w;
        }
        uint4 pk;
        pk.x = (unsigned)f2b(v0) | ((unsigned)f2b(v1) << 16);
        pk.y = (unsigned)f2b(v2) | ((unsigned)f2b(v3) << 16);
        pk.z = (unsigned)f2b(v4) | ((unsigned)f2b(v5) << 16);
        pk.w = (unsigned)f2b(v6) | ((unsigned)f2b(v7) << 16);
        *(uint4*)&Xs[r * 136 + q * 8] = pk;
    }
    __syncthreads();
    const int l = tid & 63;
    const int wid = tid >> 6;
    const int m = l & 15, g = l >> 4;
    const int wr0 = wid * 32;
    f32x4 acc[2][4];
#pragma unroll
    for (int rt = 0; rt < 2; ++rt)
#pragma unroll
        for (int ct = 0; ct < 4; ++ct) acc[rt][ct] = 0;
#pragma unroll
    for (int ks = 0; ks < 4; ++ks) {
        bf16x8 a[2], b[4];
#pragma unroll
        for (int rt = 0; rt < 2; ++rt)
            a[rt] = *(const bf16x8*)&Xs[(wr0 + rt * 16 + m) * 136 + ks * 32 + g * 8];
#pragma unroll
        for (int ct = 0; ct < 4; ++ct)
            b[ct] = *(const bf16x8*)&Wt[(ct * 16 + m) * 136 + ks * 32 + g * 8];
#pragma unroll
        for (int rt = 0; rt < 2; ++rt)
#pragma unroll
            for (int ct = 0; ct < 4; ++ct)
                acc[rt][ct] = __builtin_amdgcn_mfma_f32_16x16x32_bf16(a[rt], b[ct], acc[rt][ct], 0, 0, 0);
    }
    // epilogue: C/D layout col = lane&15, row = (lane>>4)*4 + j  [m89-verified]
#pragma unroll
    for (int rt = 0; rt < 2; ++rt)
#pragma unroll
        for (int ct = 0; ct < 4; ++ct)
#pragma unroll
            for (int j = 0; j < 4; ++j) {
                const int r = row0 + wr0 + rt * 16 + g * 4 + j;
                if (r < NN)
                    out[(size_t)r * 64 + ct * 16 + m] = __float2bfloat16(acc[rt][ct][j]);
            }
}

// ============ GEMM2 (MFMA): h[N,64] @ W2[64,64] -> out_bf16[N,64] ============
__global__ __launch_bounds__(256) void gemm2_mfma(const float* __restrict__ h,
                                                  const float* __restrict__ W,
                                                  __hip_bfloat16* __restrict__ out) {
    __shared__ unsigned short Xs[128 * 72];    // 18432 B
    __shared__ unsigned short Wt[64 * 72];     // 9216 B
    const int tid = threadIdx.x;
    const int row0 = blockIdx.x * 128;
    for (int i = tid; i < 64 * 32; i += 256) {
        const int n = i & 63, kp = i >> 6;
        const unsigned pack = (unsigned)f2b(W[(2 * kp) * 64 + n]) |
                              ((unsigned)f2b(W[(2 * kp + 1) * 64 + n]) << 16);
        *(unsigned*)&Wt[n * 72 + 2 * kp] = pack;
    }
    for (int i = tid; i < 128 * 8; i += 256) {
        const int r = i >> 3, q = i & 7;
        const int row = row0 + r;
        float v0 = 0.f, v1 = 0.f, v2 = 0.f, v3 = 0.f, v4 = 0.f, v5 = 0.f, v6 = 0.f, v7 = 0.f;
        if (row < NN) {
            const float4 a = *(const float4*)(h + (size_t)row * 64 + q * 8);
            const float4 b = *(const float4*)(h + (size_t)row * 64 + q * 8 + 4);
            v0 = a.x; v1 = a.y; v2 = a.z; v3 = a.w; v4 = b.x; v5 = b.y; v6 = b.z; v7 = b.w;
        }
        uint4 pk;
        pk.x = (unsigned)f2b(v0) | ((unsigned)f2b(v1) << 16);
        pk.y = (unsigned)f2b(v2) | ((unsigned)f2b(v3) << 16);
        pk.z = (unsigned)f2b(v4) | ((unsigned)f2b(v5) << 16);
        pk.w = (unsigned)f2b(v6) | ((unsigned)f2b(v7) << 16);
        *(uint4*)&Xs[r * 72 + q * 8] = pk;
    }
    __syncthreads();
    const int l = tid & 63;
    const int wid = tid >> 6;
    const int m = l & 15, g = l >> 4;
    const int wr0 = wid * 32;
    f32x4 acc[2][4];
#pragma unroll
    for (int rt = 0; rt < 2; ++rt)
#pragma unroll
        for (int ct = 0; ct < 4; ++ct) acc[rt][ct] = 0;
#pragma unroll
    for (int ks = 0; ks < 2; ++ks) {
        bf16x8 a[2], b[4];
#pragma unroll
        for (int rt = 0; rt < 2; ++rt)
            a[rt] = *(const bf16x8*)&Xs[(wr0 + rt * 16 + m) * 72 + ks * 32 + g * 8];
#pragma unroll
        for (int ct = 0; ct < 4; ++ct)
            b[ct] = *(const bf16x8*)&Wt[(ct * 16 + m) * 72 + ks * 32 + g * 8];
#pragma unroll
        for (int rt = 0; rt < 2; ++rt)
#pragma unroll
            for (int ct = 0; ct < 4; ++ct)
                acc[rt][ct] = __builtin_amdgcn_mfma_f32_16x16x32_bf16(a[rt], b[ct], acc[rt][ct], 0, 0, 0);
    }
#pragma unroll
    for (int rt = 0; rt < 2; ++rt)
#pragma unroll
        for (int ct = 0; ct < 4; ++ct)
#pragma unroll
            for (int j = 0; j < 4; ++j) {
                const int r = row0 + wr0 + rt * 16 + g * 4 + j;
                if (r < NN)
                    out[(size_t)r * 64 + ct * 16 + m] = __float2bfloat16(acc[rt][ct][j]);
            }
}

// ---------------- init fixed-capacity bucket cursors ----------------
__global__ void init_bcur(int* __restrict__ bcur) {
    const int t = threadIdx.x;
    if (t < NBUCK) bcur[t] = t * CAP;
}

// ---------------- bin edges (1042 blocks -> 4 blocks/CU) ----------------
__global__ __launch_bounds__(BINB) void bin_edges(const int* __restrict__ es,
                                                  const int* __restrict__ ed,
                                                  const float* __restrict__ ew,
                                                  int* __restrict__ bcur,
                                                  int2* __restrict__ srcdw) {
    __shared__ int hist[NBUCK];
    __shared__ int base[NBUCK];
    const int tid = threadIdx.x;
    const int e0 = blockIdx.x * BCHUNK;
    for (int i = tid; i < NBUCK; i += BINB) hist[i] = 0;
    __syncthreads();
    int d[3];
#pragma unroll
    for (int j = 0; j < 3; ++j) {
        const int e = e0 + j * BINB + tid;
        d[j] = (e < NE) ? ed[e] : -1;
        if (d[j] >= 0) atomicAdd(&hist[d[j] >> BSHIFT], 1);
    }
    __syncthreads();
    for (int i = tid; i < NBUCK; i += BINB) base[i] = atomicAdd(&bcur[i], hist[i]);
    __syncthreads();
    for (int i = tid; i < NBUCK; i += BINB) hist[i] = 0;
    __syncthreads();
#pragma unroll
    for (int j = 0; j < 3; ++j) {
        const int e = e0 + j * BINB + tid;
        if (d[j] >= 0) {
            const int bb = d[j] >> BSHIFT;
            const int l = atomicAdd(&hist[bb], 1);
            srcdw[base[bb] + l] = make_int2(es[e] | ((d[j] & 511) << 17), __float_as_int(ew[e]));
        }
    }
}

// ---------------- per-bucket CSR finalize (1024 threads) ----------------
__global__ __launch_bounds__(1024) void bucket_csr(const int2* __restrict__ srcdw,
                                                   const int* __restrict__ bcur,
                                                   int2* __restrict__ rng,
                                                   int2* __restrict__ edges2) {
    __shared__ int A[512], B2[512];
    const int tid = threadIdx.x;
    const int b = blockIdx.x;
    const int base = b * CAP;
    const int cnt = bcur[b] - base;
    if (tid < 512) A[tid] = 0;
    __syncthreads();
    for (int e = tid; e < cnt; e += 1024)
        atomicAdd(&A[(srcdw[base + e].x >> 17) & 511], 1);
    __syncthreads();
    const int v = (tid < 512) ? A[tid] : 0;
    int* src = A;
    int* dst = B2;
    for (int d = 1; d < 512; d <<= 1) {
        if (tid < 512) dst[tid] = src[tid] + ((tid >= d) ? src[tid - d] : 0);
        __syncthreads();
        int* t = src; src = dst; dst = t;
    }
    if (tid < 512) {
        const int incl = src[tid];
        const int excl = incl - v;
        const int node = (b << BSHIFT) + tid;
        if (node < NN) rng[node] = make_int2(base + excl, base + incl);
        dst[tid] = excl;
    }
    __syncthreads();
    for (int e = tid; e < cnt; e += 1024) {
        const int2 sw = srcdw[base + e];
        const int dl = (sw.x >> 17) & 511;
        const int pos = atomicAdd(&dst[dl], 1);
        edges2[base + pos] = make_int2(sw.x & 0x1FFFF, sw.y);
    }
}

// ---------------- CSR SpMM: 4 edges per gather instr + bias + relu ----------------
// lane = (p, f4): p = lane>>4 picks edge-of-quad, f4 = lane&15 picks 4-feature group.
__global__ __launch_bounds__(256) void spmm_csr(const __hip_bfloat16* __restrict__ feat,
                                                const int2* __restrict__ rng,
                                                const int2* __restrict__ edges2,
                                                const float* __restrict__ b,
                                                float* __restrict__ out) {
    const int w = threadIdx.x >> 6;
    const int lane = threadIdx.x & 63;
    const int n = blockIdx.x * 4 + w;
    const int2 r = rng[n];
    const int beg = r.x, end = r.y;
    const int p = lane >> 4;
    const int f4 = lane & 15;
    float a0 = 0.f, a1 = 0.f, a2 = 0.f, a3 = 0.f;
    int i = beg;
#define FMA4(G, WV)                                            \
    a0 = fmaf(__uint_as_float((G).x << 16), (WV), a0);         \
    a1 = fmaf(__uint_as_float((G).x & 0xffff0000u), (WV), a1); \
    a2 = fmaf(__uint_as_float((G).y << 16), (WV), a2);         \
    a3 = fmaf(__uint_as_float((G).y & 0xffff0000u), (WV), a3);
    for (; i + 15 < end; i += 16) {                // 16 edges, 4 gathers in flight
        const int2 e0 = edges2[i      + p];
        const int2 e1 = edges2[i + 4  + p];
        const int2 e2 = edges2[i + 8  + p];
        const int2 e3 = edges2[i + 12 + p];
        const uint2 g0 = *(const uint2*)(feat + (size_t)e0.x * 64 + f4 * 4);
        const uint2 g1 = *(const uint2*)(feat + (size_t)e1.x * 64 + f4 * 4);
        const uint2 g2 = *(const uint2*)(feat + (size_t)e2.x * 64 + f4 * 4);
        const uint2 g3 = *(const uint2*)(feat + (size_t)e3.x * 64 + f4 * 4);
        const float w0 = __int_as_float(e0.y), w1 = __int_as_float(e1.y);
        const float w2 = __int_as_float(e2.y), w3 = __int_as_float(e3.y);
        FMA4(g0, w0) FMA4(g1, w1) FMA4(g2, w2) FMA4(g3, w3)
    }
    for (; i < end; i += 4) {                      // predicated 4-edge tail
        const int idx = i + p;
        const int2 e = edges2[idx];                // overread <= 3 slots, in workspace
        const float wv = (idx < end) ? __int_as_float(e.y) : 0.f;
        const int src = e.x & 0x1FFFF;
        const uint2 g = *(const uint2*)(feat + (size_t)src * 64 + f4 * 4);
        FMA4(g, wv)
    }
#undef FMA4
    a0 += __shfl_xor(a0, 16, 64); a0 += __shfl_xor(a0, 32, 64);
    a1 += __shfl_xor(a1, 16, 64); a1 += __shfl_xor(a1, 32, 64);
    a2 += __shfl_xor(a2, 16, 64); a2 += __shfl_xor(a2, 32, 64);
    a3 += __shfl_xor(a3, 16, 64); a3 += __shfl_xor(a3, 32, 64);
    if (p == 0) {
        const float4 bv = *(const float4*)(b + f4 * 4);
        float4 o;
        o.x = fmaxf(a0 + bv.x, 0.f);
        o.y = fmaxf(a1 + bv.y, 0.f);
        o.z = fmaxf(a2 + bv.z, 0.f);
        o.w = fmaxf(a3 + bv.w, 0.f);
        *(float4*)(out + (size_t)n * 64 + f4 * 4) = o;
    }
}

// ============ head: 128 rows x 40 cols per block, register-tiled ============
__global__ __launch_bounds__(256) void head_tile(const float* __restrict__ h2,
                                                 const float* __restrict__ Wl,
                                                 const float* __restrict__ bl,
                                                 float* __restrict__ logits,
                                                 float* __restrict__ logp) {
    __shared__ float Wt[40 * 68];
    __shared__ float Xs[HROWS * 68];
    __shared__ float bs[40];
    const int tid = threadIdx.x;
    const int row0 = blockIdx.x * HROWS;
    for (int i = tid; i < 64 * 40; i += 256) {
        const int k = i / 40, c = i - k * 40;
        Wt[c * 68 + k] = Wl[i];
    }
    if (tid < 40) bs[tid] = bl[tid];
    for (int i = tid; i < HROWS * 16; i += 256) {
        const int r = i >> 4, kq = i & 15;
        const int row = row0 + r;
        float4 v = make_float4(0.f, 0.f, 0.f, 0.f);
        if (row < NN) v = *(const float4*)(h2 + (size_t)row * 64 + kq * 4);
        *(float4*)(&Xs[r * 68 + kq * 4]) = v;
    }
    __syncthreads();
    const int tcol = tid & 3;
    const int trow = tid >> 2;
    float acc[2][10] = {};
    const float* xb0 = &Xs[trow * 68];
    const float* xb1 = &Xs[(trow + 64) * 68];
    const float* wb = &Wt[(tcol * 10) * 68];
    for (int k = 0; k < 64; k += 4) {
        const float4 x0 = *(const float4*)(xb0 + k);
        const float4 x1 = *(const float4*)(xb1 + k);
#pragma unroll
        for (int c = 0; c < 10; ++c) {
            const float4 wv = *(const float4*)(wb + c * 68 + k);
            acc[0][c] = fmaf(x0.x, wv.x, acc[0][c]);
            acc[0][c] = fmaf(x0.y, wv.y, acc[0][c]);
            acc[0][c] = fmaf(x0.z, wv.z, acc[0][c]);
            acc[0][c] = fmaf(x0.w, wv.w, acc[0][c]);
            acc[1][c] = fmaf(x1.x, wv.x, acc[1][c]);
            acc[1][c] = fmaf(x1.y, wv.y, acc[1][c]);
            acc[1][c] = fmaf(x1.z, wv.z, acc[1][c]);
            acc[1][c] = fmaf(x1.w, wv.w, acc[1][c]);
        }
    }
    float bv[10];
#pragma unroll
    for (int c = 0; c < 10; ++c) bv[c] = bs[tcol * 10 + c];
#pragma unroll
    for (int r = 0; r < 2; ++r) {
        const int row = row0 + trow + r * 64;
#pragma unroll
        for (int c = 0; c < 10; ++c) acc[r][c] += bv[c];
        float m = acc[r][0];
#pragma unroll
        for (int c = 1; c < 10; ++c) m = fmaxf(m, acc[r][c]);
        m = fmaxf(m, __shfl_xor(m, 1, 64));
        m = fmaxf(m, __shfl_xor(m, 2, 64));
        float s = 0.f;
#pragma unroll
        for (int c = 0; c < 10; ++c) s += expf(acc[r][c] - m);
        s += __shfl_xor(s, 1, 64);
        s += __shfl_xor(s, 2, 64);
        const float lse = logf(s) + m;
        if (row < NN) {
            float* lg = logits + (size_t)row * 40 + tcol * 10;
            float* lp = logp   + (size_t)row * 40 + tcol * 10;
#pragma unroll
            for (int c = 0; c < 10; c += 2) {
                *(float2*)(lg + c) = make_float2(acc[r][c], acc[r][c + 1]);
                *(float2*)(lp + c) = make_float2(acc[r][c] - lse, acc[r][c + 1] - lse);
            }
        }
    }
}

extern "C" void kernel_launch(void* const* d_in, const int* in_sizes, int n_in,
                              void* d_out, int out_size, void* d_ws, size_t ws_size,
                              hipStream_t stream) {
    const float* x  = (const float*)d_in[0];
    const int*   es = (const int*)  d_in[1];
    const int*   ed = (const int*)  d_in[2];
    const float* ew = (const float*)d_in[3];
    const float* W1 = (const float*)d_in[4];
    const float* b1 = (const float*)d_in[5];
    const float* W2 = (const float*)d_in[6];
    const float* b2 = (const float*)d_in[7];
    const float* Wl = (const float*)d_in[8];
    const float* bl = (const float*)d_in[9];

    float* out    = (float*)d_out;
    float* logp   = out;                          // [N,40]
    float* h1     = logp + (size_t)NN * 40;       // [N,64]
    float* h2     = h1   + (size_t)NN * 64;       // [N,64]
    float* logits = h2   + (size_t)NN * 64;       // [N,40]

    // workspace: srcdw (dead after bucket_csr) overlays ws0 (GEMM out, bf16)
    char* wsb = (char*)d_ws;
    const size_t regionA = (size_t)NBUCK * CAP * 8;                   // 16.06 MB
    int2* srcdw = (int2*)wsb;
    __hip_bfloat16* ws0 = (__hip_bfloat16*)wsb;
    int2* edges2 = (int2*)(wsb + regionA);
    int2* rng    = (int2*)((char*)edges2 + regionA);                  // [NN]
    int*  bcur   = (int*)((char*)rng + (size_t)NN * 8);               // [NBUCK]

    const int gemmGrid = (NN + 127) / 128;        // 782

    // ---- build dest-sorted bucket-windowed CSR ----
    init_bcur<<<1, 256, 0, stream>>>(bcur);
    bin_edges<<<BINGRID, BINB, 0, stream>>>(es, ed, ew, bcur, srcdw);
    bucket_csr<<<NBUCK, 1024, 0, stream>>>(srcdw, bcur, rng, edges2);

    // ---- layer 1 ----
    gemm1_mfma<<<gemmGrid, 256, 0, stream>>>(x, W1, ws0);
    spmm_csr<<<NN / 4, 256, 0, stream>>>(ws0, rng, edges2, b1, h1);

    // ---- layer 2 ----
    gemm2_mfma<<<gemmGrid, 256, 0, stream>>>(h1, W2, ws0);
    spmm_csr<<<NN / 4, 256, 0, stream>>>(ws0, rng, edges2, b2, h2);

    // ---- head ----
    head_tile<<<(NN + HROWS - 1) / HROWS, 256, 0, stream>>>(h2, Wl, bl, logits, logp);
}

// Round 14
// 213.939 us; speedup vs baseline: 6.9030x; 1.0105x over previous
//
#include <hip/hip_runtime.h>
#include <hip/hip_bf16.h>
#include <math.h>

#define NN 100000
#define NE 1600000
#define BSHIFT 9
#define NBUCK ((NN + (1 << BSHIFT) - 1) >> BSHIFT)   // 196
#define CAP 10240
#define BINB 512
#define BCHUNK 1536
#define BINGRID ((NE + BCHUNK - 1) / BCHUNK)         // 1042
#define HROWS 128
#define NPW 8                                        // nodes per wave in spmm

typedef __attribute__((ext_vector_type(8))) short bf16x8;
typedef __attribute__((ext_vector_type(4))) float f32x4;

static __device__ inline unsigned short f2b(float f) {
    __hip_bfloat16 b = __float2bfloat16(f);
    return *reinterpret_cast<unsigned short*>(&b);
}

// ============ GEMM1 (MFMA): x[N,128] @ W1[128,64] -> out_bf16[N,64] ============
__global__ __launch_bounds__(256) void gemm1_mfma(const float* __restrict__ x,
                                                  const float* __restrict__ W,
                                                  __hip_bfloat16* __restrict__ out) {
    __shared__ unsigned short Xs[128 * 136];   // 34816 B
    __shared__ unsigned short Wt[64 * 136];    // 17408 B  (Wt[n][k])
    const int tid = threadIdx.x;
    const int row0 = blockIdx.x * 128;
    for (int i = tid; i < 64 * 64; i += 256) {
        const int n = i & 63, kp = i >> 6;
        const unsigned pack = (unsigned)f2b(W[(2 * kp) * 64 + n]) |
                              ((unsigned)f2b(W[(2 * kp + 1) * 64 + n]) << 16);
        *(unsigned*)&Wt[n * 136 + 2 * kp] = pack;
    }
    for (int i = tid; i < 128 * 16; i += 256) {
        const int r = i >> 4, q = i & 15;
        const int row = row0 + r;
        float v0 = 0.f, v1 = 0.f, v2 = 0.f, v3 = 0.f, v4 = 0.f, v5 = 0.f, v6 = 0.f, v7 = 0.f;
        if (row < NN) {
            const float4 a = *(const float4*)(x + (size_t)row * 128 + q * 8);
            const float4 b = *(const float4*)(x + (size_t)row * 128 + q * 8 + 4);
            v0 = a.x; v1 = a.y; v2 = a.z; v3 = a.w; v4 = b.x; v5 = b.y; v6 = b.z; v7 = b.w;
        }
        uint4 pk;
        pk.x = (unsigned)f2b(v0) | ((unsigned)f2b(v1) << 16);
        pk.y = (unsigned)f2b(v2) | ((unsigned)f2b(v3) << 16);
        pk.z = (unsigned)f2b(v4) | ((unsigned)f2b(v5) << 16);
        pk.w = (unsigned)f2b(v6) | ((unsigned)f2b(v7) << 16);
        *(uint4*)&Xs[r * 136 + q * 8] = pk;
    }
    __syncthreads();
    const int l = tid & 63;
    const int wid = tid >> 6;
    const int m = l & 15, g = l >> 4;
    const int wr0 = wid * 32;
    f32x4 acc[2][4];
#pragma unroll
    for (int rt = 0; rt < 2; ++rt)
#pragma unroll
        for (int ct = 0; ct < 4; ++ct) acc[rt][ct] = 0;
#pragma unroll
    for (int ks = 0; ks < 4; ++ks) {
        bf16x8 a[2], b[4];
#pragma unroll
        for (int rt = 0; rt < 2; ++rt)
            a[rt] = *(const bf16x8*)&Xs[(wr0 + rt * 16 + m) * 136 + ks * 32 + g * 8];
#pragma unroll
        for (int ct = 0; ct < 4; ++ct)
            b[ct] = *(const bf16x8*)&Wt[(ct * 16 + m) * 136 + ks * 32 + g * 8];
#pragma unroll
        for (int rt = 0; rt < 2; ++rt)
#pragma unroll
            for (int ct = 0; ct < 4; ++ct)
                acc[rt][ct] = __builtin_amdgcn_mfma_f32_16x16x32_bf16(a[rt], b[ct], acc[rt][ct], 0, 0, 0);
    }
#pragma unroll
    for (int rt = 0; rt < 2; ++rt)
#pragma unroll
        for (int ct = 0; ct < 4; ++ct)
#pragma unroll
            for (int j = 0; j < 4; ++j) {
                const int r = row0 + wr0 + rt * 16 + g * 4 + j;
                if (r < NN)
                    out[(size_t)r * 64 + ct * 16 + m] = __float2bfloat16(acc[rt][ct][j]);
            }
}

// ============ GEMM2 (MFMA): h[N,64] @ W2[64,64] -> out_bf16[N,64] ============
__global__ __launch_bounds__(256) void gemm2_mfma(const float* __restrict__ h,
                                                  const float* __restrict__ W,
                                                  __hip_bfloat16* __restrict__ out) {
    __shared__ unsigned short Xs[128 * 72];    // 18432 B
    __shared__ unsigned short Wt[64 * 72];     // 9216 B
    const int tid = threadIdx.x;
    const int row0 = blockIdx.x * 128;
    for (int i = tid; i < 64 * 32; i += 256) {
        const int n = i & 63, kp = i >> 6;
        const unsigned pack = (unsigned)f2b(W[(2 * kp) * 64 + n]) |
                              ((unsigned)f2b(W[(2 * kp + 1) * 64 + n]) << 16);
        *(unsigned*)&Wt[n * 72 + 2 * kp] = pack;
    }
    for (int i = tid; i < 128 * 8; i += 256) {
        const int r = i >> 3, q = i & 7;
        const int row = row0 + r;
        float v0 = 0.f, v1 = 0.f, v2 = 0.f, v3 = 0.f, v4 = 0.f, v5 = 0.f, v6 = 0.f, v7 = 0.f;
        if (row < NN) {
            const float4 a = *(const float4*)(h + (size_t)row * 64 + q * 8);
            const float4 b = *(const float4*)(h + (size_t)row * 64 + q * 8 + 4);
            v0 = a.x; v1 = a.y; v2 = a.z; v3 = a.w; v4 = b.x; v5 = b.y; v6 = b.z; v7 = b.w;
        }
        uint4 pk;
        pk.x = (unsigned)f2b(v0) | ((unsigned)f2b(v1) << 16);
        pk.y = (unsigned)f2b(v2) | ((unsigned)f2b(v3) << 16);
        pk.z = (unsigned)f2b(v4) | ((unsigned)f2b(v5) << 16);
        pk.w = (unsigned)f2b(v6) | ((unsigned)f2b(v7) << 16);
        *(uint4*)&Xs[r * 72 + q * 8] = pk;
    }
    __syncthreads();
    const int l = tid & 63;
    const int wid = tid >> 6;
    const int m = l & 15, g = l >> 4;
    const int wr0 = wid * 32;
    f32x4 acc[2][4];
#pragma unroll
    for (int rt = 0; rt < 2; ++rt)
#pragma unroll
        for (int ct = 0; ct < 4; ++ct) acc[rt][ct] = 0;
#pragma unroll
    for (int ks = 0; ks < 2; ++ks) {
        bf16x8 a[2], b[4];
#pragma unroll
        for (int rt = 0; rt < 2; ++rt)
            a[rt] = *(const bf16x8*)&Xs[(wr0 + rt * 16 + m) * 72 + ks * 32 + g * 8];
#pragma unroll
        for (int ct = 0; ct < 4; ++ct)
            b[ct] = *(const bf16x8*)&Wt[(ct * 16 + m) * 72 + ks * 32 + g * 8];
#pragma unroll
        for (int rt = 0; rt < 2; ++rt)
#pragma unroll
            for (int ct = 0; ct < 4; ++ct)
                acc[rt][ct] = __builtin_amdgcn_mfma_f32_16x16x32_bf16(a[rt], b[ct], acc[rt][ct], 0, 0, 0);
    }
#pragma unroll
    for (int rt = 0; rt < 2; ++rt)
#pragma unroll
        for (int ct = 0; ct < 4; ++ct)
#pragma unroll
            for (int j = 0; j < 4; ++j) {
                const int r = row0 + wr0 + rt * 16 + g * 4 + j;
                if (r < NN)
                    out[(size_t)r * 64 + ct * 16 + m] = __float2bfloat16(acc[rt][ct][j]);
            }
}

// ---------------- init fixed-capacity bucket cursors ----------------
__global__ void init_bcur(int* __restrict__ bcur) {
    const int t = threadIdx.x;
    if (t < NBUCK) bcur[t] = t * CAP;
}

// ---------------- bin edges (1042 blocks -> 4 blocks/CU) ----------------
__global__ __launch_bounds__(BINB) void bin_edges(const int* __restrict__ es,
                                                  const int* __restrict__ ed,
                                                  const float* __restrict__ ew,
                                                  int* __restrict__ bcur,
                                                  int2* __restrict__ srcdw) {
    __shared__ int hist[NBUCK];
    __shared__ int base[NBUCK];
    const int tid = threadIdx.x;
    const int e0 = blockIdx.x * BCHUNK;
    for (int i = tid; i < NBUCK; i += BINB) hist[i] = 0;
    __syncthreads();
    int d[3];
#pragma unroll
    for (int j = 0; j < 3; ++j) {
        const int e = e0 + j * BINB + tid;
        d[j] = (e < NE) ? ed[e] : -1;
        if (d[j] >= 0) atomicAdd(&hist[d[j] >> BSHIFT], 1);
    }
    __syncthreads();
    for (int i = tid; i < NBUCK; i += BINB) base[i] = atomicAdd(&bcur[i], hist[i]);
    __syncthreads();
    for (int i = tid; i < NBUCK; i += BINB) hist[i] = 0;
    __syncthreads();
#pragma unroll
    for (int j = 0; j < 3; ++j) {
        const int e = e0 + j * BINB + tid;
        if (d[j] >= 0) {
            const int bb = d[j] >> BSHIFT;
            const int l = atomicAdd(&hist[bb], 1);
            srcdw[base[bb] + l] = make_int2(es[e] | ((d[j] & 511) << 17), __float_as_int(ew[e]));
        }
    }
}

// ---------------- per-bucket CSR finalize (1024 threads) ----------------
__global__ __launch_bounds__(1024) void bucket_csr(const int2* __restrict__ srcdw,
                                                   const int* __restrict__ bcur,
                                                   int2* __restrict__ rng,
                                                   int2* __restrict__ edges2) {
    __shared__ int A[512], B2[512];
    const int tid = threadIdx.x;
    const int b = blockIdx.x;
    const int base = b * CAP;
    const int cnt = bcur[b] - base;
    if (tid < 512) A[tid] = 0;
    __syncthreads();
    for (int e = tid; e < cnt; e += 1024)
        atomicAdd(&A[(srcdw[base + e].x >> 17) & 511], 1);
    __syncthreads();
    const int v = (tid < 512) ? A[tid] : 0;
    int* src = A;
    int* dst = B2;
    for (int d = 1; d < 512; d <<= 1) {
        if (tid < 512) dst[tid] = src[tid] + ((tid >= d) ? src[tid - d] : 0);
        __syncthreads();
        int* t = src; src = dst; dst = t;
    }
    if (tid < 512) {
        const int incl = src[tid];
        const int excl = incl - v;
        const int node = (b << BSHIFT) + tid;
        if (node < NN) rng[node] = make_int2(base + excl, base + incl);
        dst[tid] = excl;
    }
    __syncthreads();
    for (int e = tid; e < cnt; e += 1024) {
        const int2 sw = srcdw[base + e];
        const int dl = (sw.x >> 17) & 511;
        const int pos = atomicAdd(&dst[dl], 1);
        edges2[base + pos] = make_int2(sw.x & 0x1FFFF, sw.y);
    }
}

// ---------------- CSR SpMM: 8 nodes per wave, 4 edges per gather instr ----------------
// lane = (p, f4): p = lane>>4 picks edge-of-quad, f4 = lane&15 picks 4-feature group.
__global__ __launch_bounds__(256) void spmm_csr(const __hip_bfloat16* __restrict__ feat,
                                                const int2* __restrict__ rng,
                                                const int2* __restrict__ edges2,
                                                const float* __restrict__ b,
                                                float* __restrict__ out) {
    const int w = threadIdx.x >> 6;
    const int lane = threadIdx.x & 63;
    const int n0 = (blockIdx.x * 4 + w) * NPW;
    const int p = lane >> 4;
    const int f4 = lane & 15;
    const float4 bv = *(const float4*)(b + f4 * 4);
#define FMA4(G, WV)                                            \
    a0 = fmaf(__uint_as_float((G).x << 16), (WV), a0);         \
    a1 = fmaf(__uint_as_float((G).x & 0xffff0000u), (WV), a1); \
    a2 = fmaf(__uint_as_float((G).y << 16), (WV), a2);         \
    a3 = fmaf(__uint_as_float((G).y & 0xffff0000u), (WV), a3);
#pragma unroll 1
    for (int nn = 0; nn < NPW; ++nn) {
        const int n = n0 + nn;                     // NN % 32 == 0 -> always valid
        const int2 r = rng[n];
        const int beg = r.x, end = r.y;
        float a0 = 0.f, a1 = 0.f, a2 = 0.f, a3 = 0.f;
        int i = beg;
        for (; i + 15 < end; i += 16) {            // 16 edges, 4 gathers in flight
            const int2 e0 = edges2[i      + p];
            const int2 e1 = edges2[i + 4  + p];
            const int2 e2 = edges2[i + 8  + p];
            const int2 e3 = edges2[i + 12 + p];
            const uint2 g0 = *(const uint2*)(feat + (size_t)e0.x * 64 + f4 * 4);
            const uint2 g1 = *(const uint2*)(feat + (size_t)e1.x * 64 + f4 * 4);
            const uint2 g2 = *(const uint2*)(feat + (size_t)e2.x * 64 + f4 * 4);
            const uint2 g3 = *(const uint2*)(feat + (size_t)e3.x * 64 + f4 * 4);
            const float w0 = __int_as_float(e0.y), w1 = __int_as_float(e1.y);
            const float w2 = __int_as_float(e2.y), w3 = __int_as_float(e3.y);
            FMA4(g0, w0) FMA4(g1, w1) FMA4(g2, w2) FMA4(g3, w3)
        }
        for (; i < end; i += 4) {                  // predicated 4-edge tail
            const int idx = i + p;
            const int2 e = edges2[idx];            // overread <= 3 slots, in workspace
            const float wv = (idx < end) ? __int_as_float(e.y) : 0.f;
            const int src = e.x & 0x1FFFF;
            const uint2 g = *(const uint2*)(feat + (size_t)src * 64 + f4 * 4);
            FMA4(g, wv)
        }
        a0 += __shfl_xor(a0, 16, 64); a0 += __shfl_xor(a0, 32, 64);
        a1 += __shfl_xor(a1, 16, 64); a1 += __shfl_xor(a1, 32, 64);
        a2 += __shfl_xor(a2, 16, 64); a2 += __shfl_xor(a2, 32, 64);
        a3 += __shfl_xor(a3, 16, 64); a3 += __shfl_xor(a3, 32, 64);
        if (p == 0) {
            float4 o;
            o.x = fmaxf(a0 + bv.x, 0.f);
            o.y = fmaxf(a1 + bv.y, 0.f);
            o.z = fmaxf(a2 + bv.z, 0.f);
            o.w = fmaxf(a3 + bv.w, 0.f);
            *(float4*)(out + (size_t)n * 64 + f4 * 4) = o;
        }
    }
#undef FMA4
}

// ============ head: 128 rows x 40 cols per block, register-tiled ============
__global__ __launch_bounds__(256) void head_tile(const float* __restrict__ h2,
                                                 const float* __restrict__ Wl,
                                                 const float* __restrict__ bl,
                                                 float* __restrict__ logits,
                                                 float* __restrict__ logp) {
    __shared__ float Wt[40 * 68];
    __shared__ float Xs[HROWS * 68];
    __shared__ float bs[40];
    const int tid = threadIdx.x;
    const int row0 = blockIdx.x * HROWS;
    for (int i = tid; i < 64 * 40; i += 256) {
        const int k = i / 40, c = i - k * 40;
        Wt[c * 68 + k] = Wl[i];
    }
    if (tid < 40) bs[tid] = bl[tid];
    for (int i = tid; i < HROWS * 16; i += 256) {
        const int r = i >> 4, kq = i & 15;
        const int row = row0 + r;
        float4 v = make_float4(0.f, 0.f, 0.f, 0.f);
        if (row < NN) v = *(const float4*)(h2 + (size_t)row * 64 + kq * 4);
        *(float4*)(&Xs[r * 68 + kq * 4]) = v;
    }
    __syncthreads();
    const int tcol = tid & 3;
    const int trow = tid >> 2;
    float acc[2][10] = {};
    const float* xb0 = &Xs[trow * 68];
    const float* xb1 = &Xs[(trow + 64) * 68];
    const float* wb = &Wt[(tcol * 10) * 68];
    for (int k = 0; k < 64; k += 4) {
        const float4 x0 = *(const float4*)(xb0 + k);
        const float4 x1 = *(const float4*)(xb1 + k);
#pragma unroll
        for (int c = 0; c < 10; ++c) {
            const float4 wv = *(const float4*)(wb + c * 68 + k);
            acc[0][c] = fmaf(x0.x, wv.x, acc[0][c]);
            acc[0][c] = fmaf(x0.y, wv.y, acc[0][c]);
            acc[0][c] = fmaf(x0.z, wv.z, acc[0][c]);
            acc[0][c] = fmaf(x0.w, wv.w, acc[0][c]);
            acc[1][c] = fmaf(x1.x, wv.x, acc[1][c]);
            acc[1][c] = fmaf(x1.y, wv.y, acc[1][c]);
            acc[1][c] = fmaf(x1.z, wv.z, acc[1][c]);
            acc[1][c] = fmaf(x1.w, wv.w, acc[1][c]);
        }
    }
    float bv[10];
#pragma unroll
    for (int c = 0; c < 10; ++c) bv[c] = bs[tcol * 10 + c];
#pragma unroll
    for (int r = 0; r < 2; ++r) {
        const int row = row0 + trow + r * 64;
#pragma unroll
        for (int c = 0; c < 10; ++c) acc[r][c] += bv[c];
        float m = acc[r][0];
#pragma unroll
        for (int c = 1; c < 10; ++c) m = fmaxf(m, acc[r][c]);
        m = fmaxf(m, __shfl_xor(m, 1, 64));
        m = fmaxf(m, __shfl_xor(m, 2, 64));
        float s = 0.f;
#pragma unroll
        for (int c = 0; c < 10; ++c) s += expf(acc[r][c] - m);
        s += __shfl_xor(s, 1, 64);
        s += __shfl_xor(s, 2, 64);
        const float lse = logf(s) + m;
        if (row < NN) {
            float* lg = logits + (size_t)row * 40 + tcol * 10;
            float* lp = logp   + (size_t)row * 40 + tcol * 10;
#pragma unroll
            for (int c = 0; c < 10; c += 2) {
                *(float2*)(lg + c) = make_float2(acc[r][c], acc[r][c + 1]);
                *(float2*)(lp + c) = make_float2(acc[r][c] - lse, acc[r][c + 1] - lse);
            }
        }
    }
}

extern "C" void kernel_launch(void* const* d_in, const int* in_sizes, int n_in,
                              void* d_out, int out_size, void* d_ws, size_t ws_size,
                              hipStream_t stream) {
    const float* x  = (const float*)d_in[0];
    const int*   es = (const int*)  d_in[1];
    const int*   ed = (const int*)  d_in[2];
    const float* ew = (const float*)d_in[3];
    const float* W1 = (const float*)d_in[4];
    const float* b1 = (const float*)d_in[5];
    const float* W2 = (const float*)d_in[6];
    const float* b2 = (const float*)d_in[7];
    const float* Wl = (const float*)d_in[8];
    const float* bl = (const float*)d_in[9];

    float* out    = (float*)d_out;
    float* logp   = out;                          // [N,40]
    float* h1     = logp + (size_t)NN * 40;       // [N,64]
    float* h2     = h1   + (size_t)NN * 64;       // [N,64]
    float* logits = h2   + (size_t)NN * 64;       // [N,40]

    // workspace: srcdw (dead after bucket_csr) overlays ws0 (GEMM out, bf16)
    char* wsb = (char*)d_ws;
    const size_t regionA = (size_t)NBUCK * CAP * 8;                   // 16.06 MB
    int2* srcdw = (int2*)wsb;
    __hip_bfloat16* ws0 = (__hip_bfloat16*)wsb;
    int2* edges2 = (int2*)(wsb + regionA);
    int2* rng    = (int2*)((char*)edges2 + regionA);                  // [NN]
    int*  bcur   = (int*)((char*)rng + (size_t)NN * 8);               // [NBUCK]

    const int gemmGrid = (NN + 127) / 128;        // 782
    const int spmmGrid = NN / (4 * NPW);          // 3125

    // ---- build dest-sorted bucket-windowed CSR ----
    init_bcur<<<1, 256, 0, stream>>>(bcur);
    bin_edges<<<BINGRID, BINB, 0, stream>>>(es, ed, ew, bcur, srcdw);
    bucket_csr<<<NBUCK, 1024, 0, stream>>>(srcdw, bcur, rng, edges2);

    // ---- layer 1 ----
    gemm1_mfma<<<gemmGrid, 256, 0, stream>>>(x, W1, ws0);
    spmm_csr<<<spmmGrid, 256, 0, stream>>>(ws0, rng, edges2, b1, h1);

    // ---- layer 2 ----
    gemm2_mfma<<<gemmGrid, 256, 0, stream>>>(h1, W2, ws0);
    spmm_csr<<<spmmGrid, 256, 0, stream>>>(ws0, rng, edges2, b2, h2);

    // ---- head ----
    head_tile<<<(NN + HROWS - 1) / HROWS, 256, 0, stream>>>(h2, Wl, bl, logits, logp);
}

// Round 15
// 202.572 us; speedup vs baseline: 7.2904x; 1.0561x over previous
//
#include <hip/hip_runtime.h>
#include <hip/hip_bf16.h>
#include <math.h>

#define NN 100000
#define NE 1600000
#define BSHIFT 9
#define NBUCK ((NN + (1 << BSHIFT) - 1) >> BSHIFT)   // 196
#define CAP 10240
#define BINB 512
#define BCHUNK 1536
#define BINGRID ((NE + BCHUNK - 1) / BCHUNK)         // 1042
#define HROWS 128
#define NPW 8                                        // nodes per wave in spmm

typedef __attribute__((ext_vector_type(8))) short bf16x8;
typedef __attribute__((ext_vector_type(4))) float f32x4;

static __device__ inline unsigned short f2b(float f) {
    __hip_bfloat16 b = __float2bfloat16(f);
    return *reinterpret_cast<unsigned short*>(&b);
}

// ============ GEMM1 (MFMA): x[N,128] @ W1[128,64] -> out_bf16[N,64] ============
__global__ __launch_bounds__(256) void gemm1_mfma(const float* __restrict__ x,
                                                  const float* __restrict__ W,
                                                  __hip_bfloat16* __restrict__ out) {
    __shared__ unsigned short Xs[128 * 136];   // 34816 B
    __shared__ unsigned short Wt[64 * 136];    // 17408 B  (Wt[n][k])
    const int tid = threadIdx.x;
    const int row0 = blockIdx.x * 128;
    for (int i = tid; i < 64 * 64; i += 256) {
        const int n = i & 63, kp = i >> 6;
        const unsigned pack = (unsigned)f2b(W[(2 * kp) * 64 + n]) |
                              ((unsigned)f2b(W[(2 * kp + 1) * 64 + n]) << 16);
        *(unsigned*)&Wt[n * 136 + 2 * kp] = pack;
    }
    for (int i = tid; i < 128 * 16; i += 256) {
        const int r = i >> 4, q = i & 15;
        const int row = row0 + r;
        float v0 = 0.f, v1 = 0.f, v2 = 0.f, v3 = 0.f, v4 = 0.f, v5 = 0.f, v6 = 0.f, v7 = 0.f;
        if (row < NN) {
            const float4 a = *(const float4*)(x + (size_t)row * 128 + q * 8);
            const float4 b = *(const float4*)(x + (size_t)row * 128 + q * 8 + 4);
            v0 = a.x; v1 = a.y; v2 = a.z; v3 = a.w; v4 = b.x; v5 = b.y; v6 = b.z; v7 = b.w;
        }
        uint4 pk;
        pk.x = (unsigned)f2b(v0) | ((unsigned)f2b(v1) << 16);
        pk.y = (unsigned)f2b(v2) | ((unsigned)f2b(v3) << 16);
        pk.z = (unsigned)f2b(v4) | ((unsigned)f2b(v5) << 16);
        pk.w = (unsigned)f2b(v6) | ((unsigned)f2b(v7) << 16);
        *(uint4*)&Xs[r * 136 + q * 8] = pk;
    }
    __syncthreads();
    const int l = tid & 63;
    const int wid = tid >> 6;
    const int m = l & 15, g = l >> 4;
    const int wr0 = wid * 32;
    f32x4 acc[2][4];
#pragma unroll
    for (int rt = 0; rt < 2; ++rt)
#pragma unroll
        for (int ct = 0; ct < 4; ++ct) acc[rt][ct] = 0;
#pragma unroll
    for (int ks = 0; ks < 4; ++ks) {
        bf16x8 a[2], b[4];
#pragma unroll
        for (int rt = 0; rt < 2; ++rt)
            a[rt] = *(const bf16x8*)&Xs[(wr0 + rt * 16 + m) * 136 + ks * 32 + g * 8];
#pragma unroll
        for (int ct = 0; ct < 4; ++ct)
            b[ct] = *(const bf16x8*)&Wt[(ct * 16 + m) * 136 + ks * 32 + g * 8];
#pragma unroll
        for (int rt = 0; rt < 2; ++rt)
#pragma unroll
            for (int ct = 0; ct < 4; ++ct)
                acc[rt][ct] = __builtin_amdgcn_mfma_f32_16x16x32_bf16(a[rt], b[ct], acc[rt][ct], 0, 0, 0);
    }
#pragma unroll
    for (int rt = 0; rt < 2; ++rt)
#pragma unroll
        for (int ct = 0; ct < 4; ++ct)
#pragma unroll
            for (int j = 0; j < 4; ++j) {
                const int r = row0 + wr0 + rt * 16 + g * 4 + j;
                if (r < NN)
                    out[(size_t)r * 64 + ct * 16 + m] = __float2bfloat16(acc[rt][ct][j]);
            }
}

// ============ GEMM2 (MFMA): h[N,64] @ W2[64,64] -> out_bf16[N,64] ============
__global__ __launch_bounds__(256) void gemm2_mfma(const float* __restrict__ h,
                                                  const float* __restrict__ W,
                                                  __hip_bfloat16* __restrict__ out) {
    __shared__ unsigned short Xs[128 * 72];    // 18432 B
    __shared__ unsigned short Wt[64 * 72];     // 9216 B
    const int tid = threadIdx.x;
    const int row0 = blockIdx.x * 128;
    for (int i = tid; i < 64 * 32; i += 256) {
        const int n = i & 63, kp = i >> 6;
        const unsigned pack = (unsigned)f2b(W[(2 * kp) * 64 + n]) |
                              ((unsigned)f2b(W[(2 * kp + 1) * 64 + n]) << 16);
        *(unsigned*)&Wt[n * 72 + 2 * kp] = pack;
    }
    for (int i = tid; i < 128 * 8; i += 256) {
        const int r = i >> 3, q = i & 7;
        const int row = row0 + r;
        float v0 = 0.f, v1 = 0.f, v2 = 0.f, v3 = 0.f, v4 = 0.f, v5 = 0.f, v6 = 0.f, v7 = 0.f;
        if (row < NN) {
            const float4 a = *(const float4*)(h + (size_t)row * 64 + q * 8);
            const float4 b = *(const float4*)(h + (size_t)row * 64 + q * 8 + 4);
            v0 = a.x; v1 = a.y; v2 = a.z; v3 = a.w; v4 = b.x; v5 = b.y; v6 = b.z; v7 = b.w;
        }
        uint4 pk;
        pk.x = (unsigned)f2b(v0) | ((unsigned)f2b(v1) << 16);
        pk.y = (unsigned)f2b(v2) | ((unsigned)f2b(v3) << 16);
        pk.z = (unsigned)f2b(v4) | ((unsigned)f2b(v5) << 16);
        pk.w = (unsigned)f2b(v6) | ((unsigned)f2b(v7) << 16);
        *(uint4*)&Xs[r * 72 + q * 8] = pk;
    }
    __syncthreads();
    const int l = tid & 63;
    const int wid = tid >> 6;
    const int m = l & 15, g = l >> 4;
    const int wr0 = wid * 32;
    f32x4 acc[2][4];
#pragma unroll
    for (int rt = 0; rt < 2; ++rt)
#pragma unroll
        for (int ct = 0; ct < 4; ++ct) acc[rt][ct] = 0;
#pragma unroll
    for (int ks = 0; ks < 2; ++ks) {
        bf16x8 a[2], b[4];
#pragma unroll
        for (int rt = 0; rt < 2; ++rt)
            a[rt] = *(const bf16x8*)&Xs[(wr0 + rt * 16 + m) * 72 + ks * 32 + g * 8];
#pragma unroll
        for (int ct = 0; ct < 4; ++ct)
            b[ct] = *(const bf16x8*)&Wt[(ct * 16 + m) * 72 + ks * 32 + g * 8];
#pragma unroll
        for (int rt = 0; rt < 2; ++rt)
#pragma unroll
            for (int ct = 0; ct < 4; ++ct)
                acc[rt][ct] = __builtin_amdgcn_mfma_f32_16x16x32_bf16(a[rt], b[ct], acc[rt][ct], 0, 0, 0);
    }
#pragma unroll
    for (int rt = 0; rt < 2; ++rt)
#pragma unroll
        for (int ct = 0; ct < 4; ++ct)
#pragma unroll
            for (int j = 0; j < 4; ++j) {
                const int r = row0 + wr0 + rt * 16 + g * 4 + j;
                if (r < NN)
                    out[(size_t)r * 64 + ct * 16 + m] = __float2bfloat16(acc[rt][ct][j]);
            }
}

// ---------------- init fixed-capacity bucket cursors ----------------
__global__ void init_bcur(int* __restrict__ bcur) {
    const int t = threadIdx.x;
    if (t < NBUCK) bcur[t] = t * CAP;
}

// ---------------- bin edges (1042 blocks -> 4 blocks/CU) ----------------
__global__ __launch_bounds__(BINB) void bin_edges(const int* __restrict__ es,
                                                  const int* __restrict__ ed,
                                                  const float* __restrict__ ew,
                                                  int* __restrict__ bcur,
                                                  int2* __restrict__ srcdw) {
    __shared__ int hist[NBUCK];
    __shared__ int base[NBUCK];
    const int tid = threadIdx.x;
    const int e0 = blockIdx.x * BCHUNK;
    for (int i = tid; i < NBUCK; i += BINB) hist[i] = 0;
    __syncthreads();
    int d[3];
#pragma unroll
    for (int j = 0; j < 3; ++j) {
        const int e = e0 + j * BINB + tid;
        d[j] = (e < NE) ? ed[e] : -1;
        if (d[j] >= 0) atomicAdd(&hist[d[j] >> BSHIFT], 1);
    }
    __syncthreads();
    for (int i = tid; i < NBUCK; i += BINB) base[i] = atomicAdd(&bcur[i], hist[i]);
    __syncthreads();
    for (int i = tid; i < NBUCK; i += BINB) hist[i] = 0;
    __syncthreads();
#pragma unroll
    for (int j = 0; j < 3; ++j) {
        const int e = e0 + j * BINB + tid;
        if (d[j] >= 0) {
            const int bb = d[j] >> BSHIFT;
            const int l = atomicAdd(&hist[bb], 1);
            srcdw[base[bb] + l] = make_int2(es[e] | ((d[j] & 511) << 17), __float_as_int(ew[e]));
        }
    }
}

// ---------------- per-bucket CSR finalize (1024 threads) ----------------
__global__ __launch_bounds__(1024) void bucket_csr(const int2* __restrict__ srcdw,
                                                   const int* __restrict__ bcur,
                                                   int2* __restrict__ rng,
                                                   int2* __restrict__ edges2) {
    __shared__ int A[512], B2[512];
    const int tid = threadIdx.x;
    const int b = blockIdx.x;
    const int base = b * CAP;
    const int cnt = bcur[b] - base;
    if (tid < 512) A[tid] = 0;
    __syncthreads();
    for (int e = tid; e < cnt; e += 1024)
        atomicAdd(&A[(srcdw[base + e].x >> 17) & 511], 1);
    __syncthreads();
    const int v = (tid < 512) ? A[tid] : 0;
    int* src = A;
    int* dst = B2;
    for (int d = 1; d < 512; d <<= 1) {
        if (tid < 512) dst[tid] = src[tid] + ((tid >= d) ? src[tid - d] : 0);
        __syncthreads();
        int* t = src; src = dst; dst = t;
    }
    if (tid < 512) {
        const int incl = src[tid];
        const int excl = incl - v;
        const int node = (b << BSHIFT) + tid;
        if (node < NN) rng[node] = make_int2(base + excl, base + incl);
        dst[tid] = excl;
    }
    __syncthreads();
    for (int e = tid; e < cnt; e += 1024) {
        const int2 sw = srcdw[base + e];
        const int dl = (sw.x >> 17) & 511;
        const int pos = atomicAdd(&dst[dl], 1);
        edges2[base + pos] = make_int2(sw.x & 0x1FFFF, sw.y);
    }
}

// ---------------- CSR SpMM: 8 nodes/wave, 8 edges per gather instr ----------------
// lane = (p, f8): p = lane>>3 picks edge-of-oct, f8 = lane&7 picks 8-feature group (16B).
__global__ __launch_bounds__(256) void spmm_csr(const __hip_bfloat16* __restrict__ feat,
                                                const int2* __restrict__ rng,
                                                const int2* __restrict__ edges2,
                                                const float* __restrict__ b,
                                                float* __restrict__ out) {
    // bijective XCD swizzle (m204): works for gridDim % 8 != 0
    const int nwg = gridDim.x;
    const int q = nwg >> 3, rr = nwg & 7;
    const int xcd = blockIdx.x & 7;
    const int sub = blockIdx.x >> 3;
    const int swz = (xcd < rr ? xcd * (q + 1) : rr * (q + 1) + (xcd - rr) * q) + sub;
    const int w = threadIdx.x >> 6;
    const int lane = threadIdx.x & 63;
    const int n0 = (swz * 4 + w) * NPW;
    const int p = lane >> 3;
    const int f8 = lane & 7;
    const float4 bv0 = *(const float4*)(b + f8 * 8);
    const float4 bv1 = *(const float4*)(b + f8 * 8 + 4);
    const int2 r8 = rng[n0 + f8];                  // lanes 0..7 hold the 8 nodes' ranges
#define FMA8(G, WV)                                            \
    a0 = fmaf(__uint_as_float((G).x << 16), (WV), a0);         \
    a1 = fmaf(__uint_as_float((G).x & 0xffff0000u), (WV), a1); \
    a2 = fmaf(__uint_as_float((G).y << 16), (WV), a2);         \
    a3 = fmaf(__uint_as_float((G).y & 0xffff0000u), (WV), a3); \
    a4 = fmaf(__uint_as_float((G).z << 16), (WV), a4);         \
    a5 = fmaf(__uint_as_float((G).z & 0xffff0000u), (WV), a5); \
    a6 = fmaf(__uint_as_float((G).w << 16), (WV), a6);         \
    a7 = fmaf(__uint_as_float((G).w & 0xffff0000u), (WV), a7);
#define RED(A) A += __shfl_xor(A, 8, 64); A += __shfl_xor(A, 16, 64); A += __shfl_xor(A, 32, 64);
#pragma unroll 1
    for (int nn = 0; nn < NPW; ++nn) {
        const int n = n0 + nn;                     // NN % 32 == 0 -> always valid
        const int beg = __shfl(r8.x, nn, 64);
        const int end = __shfl(r8.y, nn, 64);
        float a0 = 0.f, a1 = 0.f, a2 = 0.f, a3 = 0.f;
        float a4 = 0.f, a5 = 0.f, a6 = 0.f, a7 = 0.f;
        int i = beg;
        for (; i + 15 < end; i += 16) {            // 16 edges, 2 oct-gathers in flight
            const int2 e0 = edges2[i + p];
            const int2 e1 = edges2[i + 8 + p];
            const uint4 g0 = *(const uint4*)(feat + (size_t)e0.x * 64 + f8 * 8);
            const uint4 g1 = *(const uint4*)(feat + (size_t)e1.x * 64 + f8 * 8);
            const float w0 = __int_as_float(e0.y), w1 = __int_as_float(e1.y);
            FMA8(g0, w0) FMA8(g1, w1)
        }
        for (; i < end; i += 8) {                  // predicated 8-edge tail
            const int idx = i + p;
            const int2 e = edges2[idx];            // overread <= 7 slots: inside bucket window
            const float wv = (idx < end) ? __int_as_float(e.y) : 0.f;
            const uint4 g = *(const uint4*)(feat + (size_t)(e.x & 0x1FFFF) * 64 + f8 * 8);
            FMA8(g, wv)
        }
        RED(a0) RED(a1) RED(a2) RED(a3) RED(a4) RED(a5) RED(a6) RED(a7)
        if (p == 0) {                              // lanes 0..7 write the 256B row
            float4 o0, o1;
            o0.x = fmaxf(a0 + bv0.x, 0.f);
            o0.y = fmaxf(a1 + bv0.y, 0.f);
            o0.z = fmaxf(a2 + bv0.z, 0.f);
            o0.w = fmaxf(a3 + bv0.w, 0.f);
            o1.x = fmaxf(a4 + bv1.x, 0.f);
            o1.y = fmaxf(a5 + bv1.y, 0.f);
            o1.z = fmaxf(a6 + bv1.z, 0.f);
            o1.w = fmaxf(a7 + bv1.w, 0.f);
            *(float4*)(out + (size_t)n * 64 + f8 * 8) = o0;
            *(float4*)(out + (size_t)n * 64 + f8 * 8 + 4) = o1;
        }
    }
#undef FMA8
#undef RED
}

// ============ head: 128 rows x 40 cols per block, register-tiled ============
__global__ __launch_bounds__(256) void head_tile(const float* __restrict__ h2,
                                                 const float* __restrict__ Wl,
                                                 const float* __restrict__ bl,
                                                 float* __restrict__ logits,
                                                 float* __restrict__ logp) {
    __shared__ float Wt[40 * 68];
    __shared__ float Xs[HROWS * 68];
    __shared__ float bs[40];
    const int tid = threadIdx.x;
    const int row0 = blockIdx.x * HROWS;
    for (int i = tid; i < 64 * 40; i += 256) {
        const int k = i / 40, c = i - k * 40;
        Wt[c * 68 + k] = Wl[i];
    }
    if (tid < 40) bs[tid] = bl[tid];
    for (int i = tid; i < HROWS * 16; i += 256) {
        const int r = i >> 4, kq = i & 15;
        const int row = row0 + r;
        float4 v = make_float4(0.f, 0.f, 0.f, 0.f);
        if (row < NN) v = *(const float4*)(h2 + (size_t)row * 64 + kq * 4);
        *(float4*)(&Xs[r * 68 + kq * 4]) = v;
    }
    __syncthreads();
    const int tcol = tid & 3;
    const int trow = tid >> 2;
    float acc[2][10] = {};
    const float* xb0 = &Xs[trow * 68];
    const float* xb1 = &Xs[(trow + 64) * 68];
    const float* wb = &Wt[(tcol * 10) * 68];
    for (int k = 0; k < 64; k += 4) {
        const float4 x0 = *(const float4*)(xb0 + k);
        const float4 x1 = *(const float4*)(xb1 + k);
#pragma unroll
        for (int c = 0; c < 10; ++c) {
            const float4 wv = *(const float4*)(wb + c * 68 + k);
            acc[0][c] = fmaf(x0.x, wv.x, acc[0][c]);
            acc[0][c] = fmaf(x0.y, wv.y, acc[0][c]);
            acc[0][c] = fmaf(x0.z, wv.z, acc[0][c]);
            acc[0][c] = fmaf(x0.w, wv.w, acc[0][c]);
            acc[1][c] = fmaf(x1.x, wv.x, acc[1][c]);
            acc[1][c] = fmaf(x1.y, wv.y, acc[1][c]);
            acc[1][c] = fmaf(x1.z, wv.z, acc[1][c]);
            acc[1][c] = fmaf(x1.w, wv.w, acc[1][c]);
        }
    }
    float bv[10];
#pragma unroll
    for (int c = 0; c < 10; ++c) bv[c] = bs[tcol * 10 + c];
#pragma unroll
    for (int r = 0; r < 2; ++r) {
        const int row = row0 + trow + r * 64;
#pragma unroll
        for (int c = 0; c < 10; ++c) acc[r][c] += bv[c];
        float m = acc[r][0];
#pragma unroll
        for (int c = 1; c < 10; ++c) m = fmaxf(m, acc[r][c]);
        m = fmaxf(m, __shfl_xor(m, 1, 64));
        m = fmaxf(m, __shfl_xor(m, 2, 64));
        float s = 0.f;
#pragma unroll
        for (int c = 0; c < 10; ++c) s += expf(acc[r][c] - m);
        s += __shfl_xor(s, 1, 64);
        s += __shfl_xor(s, 2, 64);
        const float lse = logf(s) + m;
        if (row < NN) {
            float* lg = logits + (size_t)row * 40 + tcol * 10;
            float* lp = logp   + (size_t)row * 40 + tcol * 10;
#pragma unroll
            for (int c = 0; c < 10; c += 2) {
                *(float2*)(lg + c) = make_float2(acc[r][c], acc[r][c + 1]);
                *(float2*)(lp + c) = make_float2(acc[r][c] - lse, acc[r][c + 1] - lse);
            }
        }
    }
}

extern "C" void kernel_launch(void* const* d_in, const int* in_sizes, int n_in,
                              void* d_out, int out_size, void* d_ws, size_t ws_size,
                              hipStream_t stream) {
    const float* x  = (const float*)d_in[0];
    const int*   es = (const int*)  d_in[1];
    const int*   ed = (const int*)  d_in[2];
    const float* ew = (const float*)d_in[3];
    const float* W1 = (const float*)d_in[4];
    const float* b1 = (const float*)d_in[5];
    const float* W2 = (const float*)d_in[6];
    const float* b2 = (const float*)d_in[7];
    const float* Wl = (const float*)d_in[8];
    const float* bl = (const float*)d_in[9];

    float* out    = (float*)d_out;
    float* logp   = out;                          // [N,40]
    float* h1     = logp + (size_t)NN * 40;       // [N,64]
    float* h2     = h1   + (size_t)NN * 64;       // [N,64]
    float* logits = h2   + (size_t)NN * 64;       // [N,40]

    // workspace: srcdw (dead after bucket_csr) overlays ws0 (GEMM out, bf16)
    char* wsb = (char*)d_ws;
    const size_t regionA = (size_t)NBUCK * CAP * 8;                   // 16.06 MB
    int2* srcdw = (int2*)wsb;
    __hip_bfloat16* ws0 = (__hip_bfloat16*)wsb;
    int2* edges2 = (int2*)(wsb + regionA);
    int2* rng    = (int2*)((char*)edges2 + regionA);                  // [NN]
    int*  bcur   = (int*)((char*)rng + (size_t)NN * 8);               // [NBUCK]

    const int gemmGrid = (NN + 127) / 128;        // 782
    const int spmmGrid = NN / (4 * NPW);          // 3125

    // ---- build dest-sorted bucket-windowed CSR ----
    init_bcur<<<1, 256, 0, stream>>>(bcur);
    bin_edges<<<BINGRID, BINB, 0, stream>>>(es, ed, ew, bcur, srcdw);
    bucket_csr<<<NBUCK, 1024, 0, stream>>>(srcdw, bcur, rng, edges2);

    // ---- layer 1 ----
    gemm1_mfma<<<gemmGrid, 256, 0, stream>>>(x, W1, ws0);
    spmm_csr<<<spmmGrid, 256, 0, stream>>>(ws0, rng, edges2, b1, h1);

    // ---- layer 2 ----
    gemm2_mfma<<<gemmGrid, 256, 0, stream>>>(h1, W2, ws0);
    spmm_csr<<<spmmGrid, 256, 0, stream>>>(ws0, rng, edges2, b2, h2);

    // ---- head ----
    head_tile<<<(NN + HROWS - 1) / HROWS, 256, 0, stream>>>(h2, Wl, bl, logits, logp);
}

// Round 16
// 189.049 us; speedup vs baseline: 7.8119x; 1.0715x over previous
//
#include <hip/hip_runtime.h>
#include <hip/hip_bf16.h>
#include <math.h>

#define NN 100000
#define NE 1600000
#define BSHIFT 9
#define NBUCK ((NN + (1 << BSHIFT) - 1) >> BSHIFT)   // 196
#define CAP 10240
#define BCHUNK 1536
#define BINGRID ((NE + BCHUNK - 1) / BCHUNK)         // 1042
#define G1GRID ((NN + 127) / 128)                    // 782
#define HROWS 128
#define NPW 8

typedef __attribute__((ext_vector_type(8))) short bf16x8;
typedef __attribute__((ext_vector_type(4))) float f32x4;

static __device__ inline unsigned short f2b(float f) {
    __hip_bfloat16 b = __float2bfloat16(f);
    return *reinterpret_cast<unsigned short*>(&b);
}

// ============ FUSED: gemm1 (MFMA, blocks 0..G1GRID) ∥ bin_edges (rest) ============
// The two workloads are independent; fusing overlaps gemm1's LDS/MFMA latency with
// bin's scatter latency. LDS: gemm arrays; bin aliases the first 1.6 KB.
__global__ __launch_bounds__(256) void gemm1_bin(const float* __restrict__ x,
                                                 const float* __restrict__ W,
                                                 __hip_bfloat16* __restrict__ out,
                                                 const int* __restrict__ es,
                                                 const int* __restrict__ ed,
                                                 const float* __restrict__ ew,
                                                 int* __restrict__ bcur,
                                                 int2* __restrict__ srcdw) {
    __shared__ __align__(16) unsigned short Xs[128 * 136];   // 34816 B
    __shared__ __align__(16) unsigned short Wt[64 * 136];    // 17408 B
    const int tid = threadIdx.x;
    if (blockIdx.x < G1GRID) {
        // ---------------- gemm1: x[N,128] @ W1[128,64] -> bf16 ----------------
        const int row0 = blockIdx.x * 128;
        for (int i = tid; i < 64 * 64; i += 256) {
            const int n = i & 63, kp = i >> 6;
            const unsigned pack = (unsigned)f2b(W[(2 * kp) * 64 + n]) |
                                  ((unsigned)f2b(W[(2 * kp + 1) * 64 + n]) << 16);
            *(unsigned*)&Wt[n * 136 + 2 * kp] = pack;
        }
        for (int i = tid; i < 128 * 16; i += 256) {
            const int r = i >> 4, q = i & 15;
            const int row = row0 + r;
            float v0 = 0.f, v1 = 0.f, v2 = 0.f, v3 = 0.f, v4 = 0.f, v5 = 0.f, v6 = 0.f, v7 = 0.f;
            if (row < NN) {
                const float4 a = *(const float4*)(x + (size_t)row * 128 + q * 8);
                const float4 b = *(const float4*)(x + (size_t)row * 128 + q * 8 + 4);
                v0 = a.x; v1 = a.y; v2 = a.z; v3 = a.w; v4 = b.x; v5 = b.y; v6 = b.z; v7 = b.w;
            }
            uint4 pk;
            pk.x = (unsigned)f2b(v0) | ((unsigned)f2b(v1) << 16);
            pk.y = (unsigned)f2b(v2) | ((unsigned)f2b(v3) << 16);
            pk.z = (unsigned)f2b(v4) | ((unsigned)f2b(v5) << 16);
            pk.w = (unsigned)f2b(v6) | ((unsigned)f2b(v7) << 16);
            *(uint4*)&Xs[r * 136 + q * 8] = pk;
        }
        __syncthreads();
        const int l = tid & 63;
        const int wid = tid >> 6;
        const int m = l & 15, g = l >> 4;
        const int wr0 = wid * 32;
        f32x4 acc[2][4];
#pragma unroll
        for (int rt = 0; rt < 2; ++rt)
#pragma unroll
            for (int ct = 0; ct < 4; ++ct) acc[rt][ct] = 0;
#pragma unroll
        for (int ks = 0; ks < 4; ++ks) {
            bf16x8 a[2], b[4];
#pragma unroll
            for (int rt = 0; rt < 2; ++rt)
                a[rt] = *(const bf16x8*)&Xs[(wr0 + rt * 16 + m) * 136 + ks * 32 + g * 8];
#pragma unroll
            for (int ct = 0; ct < 4; ++ct)
                b[ct] = *(const bf16x8*)&Wt[(ct * 16 + m) * 136 + ks * 32 + g * 8];
#pragma unroll
            for (int rt = 0; rt < 2; ++rt)
#pragma unroll
                for (int ct = 0; ct < 4; ++ct)
                    acc[rt][ct] = __builtin_amdgcn_mfma_f32_16x16x32_bf16(a[rt], b[ct], acc[rt][ct], 0, 0, 0);
        }
#pragma unroll
        for (int rt = 0; rt < 2; ++rt)
#pragma unroll
            for (int ct = 0; ct < 4; ++ct)
#pragma unroll
                for (int j = 0; j < 4; ++j) {
                    const int r = row0 + wr0 + rt * 16 + g * 4 + j;
                    if (r < NN)
                        out[(size_t)r * 64 + ct * 16 + m] = __float2bfloat16(acc[rt][ct][j]);
                }
    } else {
        // ---------------- bin_edges: 256 threads, 6 edges/thread ----------------
        int* hist = (int*)Xs;
        int* base = hist + NBUCK;
        const int e0 = (blockIdx.x - G1GRID) * BCHUNK;
        for (int i = tid; i < NBUCK; i += 256) hist[i] = 0;
        __syncthreads();
        int d[6];
#pragma unroll
        for (int j = 0; j < 6; ++j) {
            const int e = e0 + j * 256 + tid;
            d[j] = (e < NE) ? ed[e] : -1;
            if (d[j] >= 0) atomicAdd(&hist[d[j] >> BSHIFT], 1);
        }
        __syncthreads();
        for (int i = tid; i < NBUCK; i += 256)
            base[i] = i * CAP + atomicAdd(&bcur[i], hist[i]);   // bcur holds relative counts
        __syncthreads();
        for (int i = tid; i < NBUCK; i += 256) hist[i] = 0;
        __syncthreads();
#pragma unroll
        for (int j = 0; j < 6; ++j) {
            const int e = e0 + j * 256 + tid;
            if (d[j] >= 0) {
                const int bb = d[j] >> BSHIFT;
                const int l2 = atomicAdd(&hist[bb], 1);
                srcdw[base[bb] + l2] = make_int2(es[e] | ((d[j] & 511) << 17), __float_as_int(ew[e]));
            }
        }
    }
}

// ============ GEMM2 (MFMA): h[N,64] @ W2[64,64] -> out_bf16[N,64] ============
__global__ __launch_bounds__(256) void gemm2_mfma(const float* __restrict__ h,
                                                  const float* __restrict__ W,
                                                  __hip_bfloat16* __restrict__ out) {
    __shared__ unsigned short Xs[128 * 72];    // 18432 B
    __shared__ unsigned short Wt[64 * 72];     // 9216 B
    const int tid = threadIdx.x;
    const int row0 = blockIdx.x * 128;
    for (int i = tid; i < 64 * 32; i += 256) {
        const int n = i & 63, kp = i >> 6;
        const unsigned pack = (unsigned)f2b(W[(2 * kp) * 64 + n]) |
                              ((unsigned)f2b(W[(2 * kp + 1) * 64 + n]) << 16);
        *(unsigned*)&Wt[n * 72 + 2 * kp] = pack;
    }
    for (int i = tid; i < 128 * 8; i += 256) {
        const int r = i >> 3, q = i & 7;
        const int row = row0 + r;
        float v0 = 0.f, v1 = 0.f, v2 = 0.f, v3 = 0.f, v4 = 0.f, v5 = 0.f, v6 = 0.f, v7 = 0.f;
        if (row < NN) {
            const float4 a = *(const float4*)(h + (size_t)row * 64 + q * 8);
            const float4 b = *(const float4*)(h + (size_t)row * 64 + q * 8 + 4);
            v0 = a.x; v1 = a.y; v2 = a.z; v3 = a.w; v4 = b.x; v5 = b.y; v6 = b.z; v7 = b.w;
        }
        uint4 pk;
        pk.x = (unsigned)f2b(v0) | ((unsigned)f2b(v1) << 16);
        pk.y = (unsigned)f2b(v2) | ((unsigned)f2b(v3) << 16);
        pk.z = (unsigned)f2b(v4) | ((unsigned)f2b(v5) << 16);
        pk.w = (unsigned)f2b(v6) | ((unsigned)f2b(v7) << 16);
        *(uint4*)&Xs[r * 72 + q * 8] = pk;
    }
    __syncthreads();
    const int l = tid & 63;
    const int wid = tid >> 6;
    const int m = l & 15, g = l >> 4;
    const int wr0 = wid * 32;
    f32x4 acc[2][4];
#pragma unroll
    for (int rt = 0; rt < 2; ++rt)
#pragma unroll
        for (int ct = 0; ct < 4; ++ct) acc[rt][ct] = 0;
#pragma unroll
    for (int ks = 0; ks < 2; ++ks) {
        bf16x8 a[2], b[4];
#pragma unroll
        for (int rt = 0; rt < 2; ++rt)
            a[rt] = *(const bf16x8*)&Xs[(wr0 + rt * 16 + m) * 72 + ks * 32 + g * 8];
#pragma unroll
        for (int ct = 0; ct < 4; ++ct)
            b[ct] = *(const bf16x8*)&Wt[(ct * 16 + m) * 72 + ks * 32 + g * 8];
#pragma unroll
        for (int rt = 0; rt < 2; ++rt)
#pragma unroll
            for (int ct = 0; ct < 4; ++ct)
                acc[rt][ct] = __builtin_amdgcn_mfma_f32_16x16x32_bf16(a[rt], b[ct], acc[rt][ct], 0, 0, 0);
    }
#pragma unroll
    for (int rt = 0; rt < 2; ++rt)
#pragma unroll
        for (int ct = 0; ct < 4; ++ct)
#pragma unroll
            for (int j = 0; j < 4; ++j) {
                const int r = row0 + wr0 + rt * 16 + g * 4 + j;
                if (r < NN)
                    out[(size_t)r * 64 + ct * 16 + m] = __float2bfloat16(acc[rt][ct][j]);
            }
}

// ---------------- per-bucket CSR finalize (1024 threads) ----------------
__global__ __launch_bounds__(1024) void bucket_csr(const int2* __restrict__ srcdw,
                                                   const int* __restrict__ bcur,
                                                   int2* __restrict__ rng,
                                                   int2* __restrict__ edges2) {
    __shared__ int A[512], B2[512];
    const int tid = threadIdx.x;
    const int b = blockIdx.x;
    const int base = b * CAP;
    const int cnt = bcur[b];                   // relative count
    if (tid < 512) A[tid] = 0;
    __syncthreads();
    for (int e = tid; e < cnt; e += 1024)
        atomicAdd(&A[(srcdw[base + e].x >> 17) & 511], 1);
    __syncthreads();
    const int v = (tid < 512) ? A[tid] : 0;
    int* src = A;
    int* dst = B2;
    for (int d = 1; d < 512; d <<= 1) {
        if (tid < 512) dst[tid] = src[tid] + ((tid >= d) ? src[tid - d] : 0);
        __syncthreads();
        int* t = src; src = dst; dst = t;
    }
    if (tid < 512) {
        const int incl = src[tid];
        const int excl = incl - v;
        const int node = (b << BSHIFT) + tid;
        if (node < NN) rng[node] = make_int2(base + excl, base + incl);
        dst[tid] = excl;
    }
    __syncthreads();
    for (int e = tid; e < cnt; e += 1024) {
        const int2 sw = srcdw[base + e];
        const int dl = (sw.x >> 17) & 511;
        const int pos = atomicAdd(&dst[dl], 1);
        edges2[base + pos] = make_int2(sw.x & 0x1FFFF, sw.y);
    }
}

// ---------------- CSR SpMM: 8 nodes/wave, 8 edges per gather instr ----------------
__global__ __launch_bounds__(256) void spmm_csr(const __hip_bfloat16* __restrict__ feat,
                                                const int2* __restrict__ rng,
                                                const int2* __restrict__ edges2,
                                                const float* __restrict__ b,
                                                float* __restrict__ out) {
    const int nwg = gridDim.x;
    const int q = nwg >> 3, rr = nwg & 7;
    const int xcd = blockIdx.x & 7;
    const int sub = blockIdx.x >> 3;
    const int swz = (xcd < rr ? xcd * (q + 1) : rr * (q + 1) + (xcd - rr) * q) + sub;
    const int w = threadIdx.x >> 6;
    const int lane = threadIdx.x & 63;
    const int n0 = (swz * 4 + w) * NPW;
    const int p = lane >> 3;
    const int f8 = lane & 7;
    const float4 bv0 = *(const float4*)(b + f8 * 8);
    const float4 bv1 = *(const float4*)(b + f8 * 8 + 4);
    const int2 r8 = rng[n0 + f8];
#define FMA8(G, WV)                                            \
    a0 = fmaf(__uint_as_float((G).x << 16), (WV), a0);         \
    a1 = fmaf(__uint_as_float((G).x & 0xffff0000u), (WV), a1); \
    a2 = fmaf(__uint_as_float((G).y << 16), (WV), a2);         \
    a3 = fmaf(__uint_as_float((G).y & 0xffff0000u), (WV), a3); \
    a4 = fmaf(__uint_as_float((G).z << 16), (WV), a4);         \
    a5 = fmaf(__uint_as_float((G).z & 0xffff0000u), (WV), a5); \
    a6 = fmaf(__uint_as_float((G).w << 16), (WV), a6);         \
    a7 = fmaf(__uint_as_float((G).w & 0xffff0000u), (WV), a7);
#define RED(A) A += __shfl_xor(A, 8, 64); A += __shfl_xor(A, 16, 64); A += __shfl_xor(A, 32, 64);
#pragma unroll 1
    for (int nn = 0; nn < NPW; ++nn) {
        const int n = n0 + nn;
        const int beg = __shfl(r8.x, nn, 64);
        const int end = __shfl(r8.y, nn, 64);
        float a0 = 0.f, a1 = 0.f, a2 = 0.f, a3 = 0.f;
        float a4 = 0.f, a5 = 0.f, a6 = 0.f, a7 = 0.f;
        int i = beg;
        for (; i + 15 < end; i += 16) {
            const int2 e0 = edges2[i + p];
            const int2 e1 = edges2[i + 8 + p];
            const uint4 g0 = *(const uint4*)(feat + (size_t)e0.x * 64 + f8 * 8);
            const uint4 g1 = *(const uint4*)(feat + (size_t)e1.x * 64 + f8 * 8);
            const float w0 = __int_as_float(e0.y), w1 = __int_as_float(e1.y);
            FMA8(g0, w0) FMA8(g1, w1)
        }
        for (; i < end; i += 8) {
            const int idx = i + p;
            const int2 e = edges2[idx];
            const float wv = (idx < end) ? __int_as_float(e.y) : 0.f;
            const uint4 g = *(const uint4*)(feat + (size_t)(e.x & 0x1FFFF) * 64 + f8 * 8);
            FMA8(g, wv)
        }
        RED(a0) RED(a1) RED(a2) RED(a3) RED(a4) RED(a5) RED(a6) RED(a7)
        if (p == 0) {
            float4 o0, o1;
            o0.x = fmaxf(a0 + bv0.x, 0.f);
            o0.y = fmaxf(a1 + bv0.y, 0.f);
            o0.z = fmaxf(a2 + bv0.z, 0.f);
            o0.w = fmaxf(a3 + bv0.w, 0.f);
            o1.x = fmaxf(a4 + bv1.x, 0.f);
            o1.y = fmaxf(a5 + bv1.y, 0.f);
            o1.z = fmaxf(a6 + bv1.z, 0.f);
            o1.w = fmaxf(a7 + bv1.w, 0.f);
            *(float4*)(out + (size_t)n * 64 + f8 * 8) = o0;
            *(float4*)(out + (size_t)n * 64 + f8 * 8 + 4) = o1;
        }
    }
#undef FMA8
#undef RED
}

// ============ head: 128 rows x 40 cols per block, register-tiled ============
__global__ __launch_bounds__(256) void head_tile(const float* __restrict__ h2,
                                                 const float* __restrict__ Wl,
                                                 const float* __restrict__ bl,
                                                 float* __restrict__ logits,
                                                 float* __restrict__ logp) {
    __shared__ float Wt[40 * 68];
    __shared__ float Xs[HROWS * 68];
    __shared__ float bs[40];
    const int tid = threadIdx.x;
    const int row0 = blockIdx.x * HROWS;
    for (int i = tid; i < 64 * 40; i += 256) {
        const int k = i / 40, c = i - k * 40;
        Wt[c * 68 + k] = Wl[i];
    }
    if (tid < 40) bs[tid] = bl[tid];
    for (int i = tid; i < HROWS * 16; i += 256) {
        const int r = i >> 4, kq = i & 15;
        const int row = row0 + r;
        float4 v = make_float4(0.f, 0.f, 0.f, 0.f);
        if (row < NN) v = *(const float4*)(h2 + (size_t)row * 64 + kq * 4);
        *(float4*)(&Xs[r * 68 + kq * 4]) = v;
    }
    __syncthreads();
    const int tcol = tid & 3;
    const int trow = tid >> 2;
    float acc[2][10] = {};
    const float* xb0 = &Xs[trow * 68];
    const float* xb1 = &Xs[(trow + 64) * 68];
    const float* wb = &Wt[(tcol * 10) * 68];
    for (int k = 0; k < 64; k += 4) {
        const float4 x0 = *(const float4*)(xb0 + k);
        const float4 x1 = *(const float4*)(xb1 + k);
#pragma unroll
        for (int c = 0; c < 10; ++c) {
            const float4 wv = *(const float4*)(wb + c * 68 + k);
            acc[0][c] = fmaf(x0.x, wv.x, acc[0][c]);
            acc[0][c] = fmaf(x0.y, wv.y, acc[0][c]);
            acc[0][c] = fmaf(x0.z, wv.z, acc[0][c]);
            acc[0][c] = fmaf(x0.w, wv.w, acc[0][c]);
            acc[1][c] = fmaf(x1.x, wv.x, acc[1][c]);
            acc[1][c] = fmaf(x1.y, wv.y, acc[1][c]);
            acc[1][c] = fmaf(x1.z, wv.z, acc[1][c]);
            acc[1][c] = fmaf(x1.w, wv.w, acc[1][c]);
        }
    }
    float bv[10];
#pragma unroll
    for (int c = 0; c < 10; ++c) bv[c] = bs[tcol * 10 + c];
#pragma unroll
    for (int r = 0; r < 2; ++r) {
        const int row = row0 + trow + r * 64;
#pragma unroll
        for (int c = 0; c < 10; ++c) acc[r][c] += bv[c];
        float m = acc[r][0];
#pragma unroll
        for (int c = 1; c < 10; ++c) m = fmaxf(m, acc[r][c]);
        m = fmaxf(m, __shfl_xor(m, 1, 64));
        m = fmaxf(m, __shfl_xor(m, 2, 64));
        float s = 0.f;
#pragma unroll
        for (int c = 0; c < 10; ++c) s += expf(acc[r][c] - m);
        s += __shfl_xor(s, 1, 64);
        s += __shfl_xor(s, 2, 64);
        const float lse = logf(s) + m;
        if (row < NN) {
            float* lg = logits + (size_t)row * 40 + tcol * 10;
            float* lp = logp   + (size_t)row * 40 + tcol * 10;
#pragma unroll
            for (int c = 0; c < 10; c += 2) {
                *(float2*)(lg + c) = make_float2(acc[r][c], acc[r][c + 1]);
                *(float2*)(lp + c) = make_float2(acc[r][c] - lse, acc[r][c + 1] - lse);
            }
        }
    }
}

extern "C" void kernel_launch(void* const* d_in, const int* in_sizes, int n_in,
                              void* d_out, int out_size, void* d_ws, size_t ws_size,
                              hipStream_t stream) {
    const float* x  = (const float*)d_in[0];
    const int*   es = (const int*)  d_in[1];
    const int*   ed = (const int*)  d_in[2];
    const float* ew = (const float*)d_in[3];
    const float* W1 = (const float*)d_in[4];
    const float* b1 = (const float*)d_in[5];
    const float* W2 = (const float*)d_in[6];
    const float* b2 = (const float*)d_in[7];
    const float* Wl = (const float*)d_in[8];
    const float* bl = (const float*)d_in[9];

    float* out    = (float*)d_out;
    float* logp   = out;                          // [N,40]
    float* h1     = logp + (size_t)NN * 40;       // [N,64]
    float* h2     = h1   + (size_t)NN * 64;       // [N,64]
    float* logits = h2   + (size_t)NN * 64;       // [N,40]

    // workspace: NO overlay now (ws0 is written concurrently with srcdw in the fused kernel)
    char* wsb = (char*)d_ws;
    const size_t regionA = (size_t)NBUCK * CAP * 8;                   // 16.06 MB
    int2* srcdw = (int2*)wsb;                                         // [NBUCK*CAP]
    int2* edges2 = (int2*)(wsb + regionA);                            // [NBUCK*CAP]
    int2* rng    = (int2*)((char*)edges2 + regionA);                  // [NN] 800 KB
    int*  bcur   = (int*)((char*)rng + (size_t)NN * 8);               // [NBUCK]
    __hip_bfloat16* ws0 = (__hip_bfloat16*)((char*)bcur + 4096);      // [N,64] bf16 12.8 MB

    const int gemmGrid = (NN + 127) / 128;        // 782
    const int spmmGrid = NN / (4 * NPW);          // 3125

    // ---- [gemm1 ∥ CSR binning] then per-bucket finalize ----
    hipMemsetAsync(bcur, 0, (size_t)NBUCK * 4, stream);
    gemm1_bin<<<G1GRID + BINGRID, 256, 0, stream>>>(x, W1, ws0, es, ed, ew, bcur, srcdw);
    bucket_csr<<<NBUCK, 1024, 0, stream>>>(srcdw, bcur, rng, edges2);

    // ---- layer 1 aggregate ----
    spmm_csr<<<spmmGrid, 256, 0, stream>>>(ws0, rng, edges2, b1, h1);

    // ---- layer 2 ----
    gemm2_mfma<<<gemmGrid, 256, 0, stream>>>(h1, W2, ws0);
    spmm_csr<<<spmmGrid, 256, 0, stream>>>(ws0, rng, edges2, b2, h2);

    // ---- head ----
    head_tile<<<(NN + HROWS - 1) / HROWS, 256, 0, stream>>>(h2, Wl, bl, logits, logp);
}

// Round 17
// 183.784 us; speedup vs baseline: 8.0357x; 1.0286x over previous
//
#include <hip/hip_runtime.h>
#include <hip/hip_bf16.h>
#include <math.h>

#define NN 100000
#define NE 1600000
#define BSHIFT 9
#define NBUCK ((NN + (1 << BSHIFT) - 1) >> BSHIFT)   // 196
#define CAP 10240
#define BCHUNK 1536
#define BINGRID ((NE + BCHUNK - 1) / BCHUNK)         // 1042
#define G1GRID ((NN + 127) / 128)                    // 782
#define HROWS 128
#define NPW 8

typedef __attribute__((ext_vector_type(8))) short bf16x8;
typedef __attribute__((ext_vector_type(4))) float f32x4;

static __device__ inline unsigned short f2b(float f) {
    __hip_bfloat16 b = __float2bfloat16(f);
    return *reinterpret_cast<unsigned short*>(&b);
}

static __device__ inline bf16x8 pack8(float4 fa, float4 fb) {
    union { bf16x8 v; unsigned u[4]; } pk;
    pk.u[0] = (unsigned)f2b(fa.x) | ((unsigned)f2b(fa.y) << 16);
    pk.u[1] = (unsigned)f2b(fa.z) | ((unsigned)f2b(fa.w) << 16);
    pk.u[2] = (unsigned)f2b(fb.x) | ((unsigned)f2b(fb.y) << 16);
    pk.u[3] = (unsigned)f2b(fb.z) | ((unsigned)f2b(fb.w) << 16);
    return pk.v;
}

// ============ FUSED: gemm1 (MFMA, blocks 0..G1GRID) ∥ bin_edges (rest) ============
// gemm1 stages ONLY W^T in LDS (17.4 KB); A-fragments load global->reg (x has no
// reuse across output cols). Both branches now get ~8 blocks/CU.
__global__ __launch_bounds__(256) void gemm1_bin(const float* __restrict__ x,
                                                 const float* __restrict__ W,
                                                 __hip_bfloat16* __restrict__ out,
                                                 const int* __restrict__ es,
                                                 const int* __restrict__ ed,
                                                 const float* __restrict__ ew,
                                                 int* __restrict__ bcur,
                                                 int2* __restrict__ srcdw) {
    __shared__ __align__(16) unsigned short Wt[64 * 136];    // 17408 B
    const int tid = threadIdx.x;
    if (blockIdx.x < G1GRID) {
        // ---------------- gemm1: x[N,128] @ W1[128,64] -> bf16 ----------------
        const int row0 = blockIdx.x * 128;
        for (int i = tid; i < 64 * 64; i += 256) {
            const int n = i & 63, kp = i >> 6;
            const unsigned pack = (unsigned)f2b(W[(2 * kp) * 64 + n]) |
                                  ((unsigned)f2b(W[(2 * kp + 1) * 64 + n]) << 16);
            *(unsigned*)&Wt[n * 136 + 2 * kp] = pack;
        }
        __syncthreads();
        const int l = tid & 63;
        const int wid = tid >> 6;
        const int m = l & 15, g = l >> 4;
        const int wr0 = wid * 32;
        f32x4 acc[2][4];
#pragma unroll
        for (int rt = 0; rt < 2; ++rt)
#pragma unroll
            for (int ct = 0; ct < 4; ++ct) acc[rt][ct] = 0;
#pragma unroll
        for (int ks = 0; ks < 4; ++ks) {
            bf16x8 a[2], b[4];
#pragma unroll
            for (int rt = 0; rt < 2; ++rt) {
                const int row = row0 + wr0 + rt * 16 + m;
                float4 fa = make_float4(0.f, 0.f, 0.f, 0.f), fb = fa;
                if (row < NN) {
                    const float* xr = x + (size_t)row * 128 + ks * 32 + g * 8;
                    fa = *(const float4*)xr;
                    fb = *(const float4*)(xr + 4);
                }
                a[rt] = pack8(fa, fb);
            }
#pragma unroll
            for (int ct = 0; ct < 4; ++ct)
                b[ct] = *(const bf16x8*)&Wt[(ct * 16 + m) * 136 + ks * 32 + g * 8];
#pragma unroll
            for (int rt = 0; rt < 2; ++rt)
#pragma unroll
                for (int ct = 0; ct < 4; ++ct)
                    acc[rt][ct] = __builtin_amdgcn_mfma_f32_16x16x32_bf16(a[rt], b[ct], acc[rt][ct], 0, 0, 0);
        }
#pragma unroll
        for (int rt = 0; rt < 2; ++rt)
#pragma unroll
            for (int ct = 0; ct < 4; ++ct)
#pragma unroll
                for (int j = 0; j < 4; ++j) {
                    const int r = row0 + wr0 + rt * 16 + g * 4 + j;
                    if (r < NN)
                        out[(size_t)r * 64 + ct * 16 + m] = __float2bfloat16(acc[rt][ct][j]);
                }
    } else {
        // ---------------- bin_edges: 256 threads, 6 edges/thread ----------------
        int* hist = (int*)Wt;
        int* base = hist + NBUCK;
        const int e0 = (blockIdx.x - G1GRID) * BCHUNK;
        for (int i = tid; i < NBUCK; i += 256) hist[i] = 0;
        __syncthreads();
        int d[6];
#pragma unroll
        for (int j = 0; j < 6; ++j) {
            const int e = e0 + j * 256 + tid;
            d[j] = (e < NE) ? ed[e] : -1;
            if (d[j] >= 0) atomicAdd(&hist[d[j] >> BSHIFT], 1);
        }
        __syncthreads();
        for (int i = tid; i < NBUCK; i += 256)
            base[i] = i * CAP + atomicAdd(&bcur[i], hist[i]);   // bcur holds relative counts
        __syncthreads();
        for (int i = tid; i < NBUCK; i += 256) hist[i] = 0;
        __syncthreads();
#pragma unroll
        for (int j = 0; j < 6; ++j) {
            const int e = e0 + j * 256 + tid;
            if (d[j] >= 0) {
                const int bb = d[j] >> BSHIFT;
                const int l2 = atomicAdd(&hist[bb], 1);
                srcdw[base[bb] + l2] = make_int2(es[e] | ((d[j] & 511) << 17), __float_as_int(ew[e]));
            }
        }
    }
}

// ============ GEMM2 (MFMA): h[N,64] @ W2[64,64] -> out_bf16[N,64] ============
// W^T-only LDS (9.2 KB); A-fragments direct from global.
__global__ __launch_bounds__(256) void gemm2_mfma(const float* __restrict__ h,
                                                  const float* __restrict__ W,
                                                  __hip_bfloat16* __restrict__ out) {
    __shared__ __align__(16) unsigned short Wt[64 * 72];     // 9216 B
    const int tid = threadIdx.x;
    const int row0 = blockIdx.x * 128;
    for (int i = tid; i < 64 * 32; i += 256) {
        const int n = i & 63, kp = i >> 6;
        const unsigned pack = (unsigned)f2b(W[(2 * kp) * 64 + n]) |
                              ((unsigned)f2b(W[(2 * kp + 1) * 64 + n]) << 16);
        *(unsigned*)&Wt[n * 72 + 2 * kp] = pack;
    }
    __syncthreads();
    const int l = tid & 63;
    const int wid = tid >> 6;
    const int m = l & 15, g = l >> 4;
    const int wr0 = wid * 32;
    f32x4 acc[2][4];
#pragma unroll
    for (int rt = 0; rt < 2; ++rt)
#pragma unroll
        for (int ct = 0; ct < 4; ++ct) acc[rt][ct] = 0;
#pragma unroll
    for (int ks = 0; ks < 2; ++ks) {
        bf16x8 a[2], b[4];
#pragma unroll
        for (int rt = 0; rt < 2; ++rt) {
            const int row = row0 + wr0 + rt * 16 + m;
            float4 fa = make_float4(0.f, 0.f, 0.f, 0.f), fb = fa;
            if (row < NN) {
                const float* hr = h + (size_t)row * 64 + ks * 32 + g * 8;
                fa = *(const float4*)hr;
                fb = *(const float4*)(hr + 4);
            }
            a[rt] = pack8(fa, fb);
        }
#pragma unroll
        for (int ct = 0; ct < 4; ++ct)
            b[ct] = *(const bf16x8*)&Wt[(ct * 16 + m) * 72 + ks * 32 + g * 8];
#pragma unroll
        for (int rt = 0; rt < 2; ++rt)
#pragma unroll
            for (int ct = 0; ct < 4; ++ct)
                acc[rt][ct] = __builtin_amdgcn_mfma_f32_16x16x32_bf16(a[rt], b[ct], acc[rt][ct], 0, 0, 0);
    }
#pragma unroll
    for (int rt = 0; rt < 2; ++rt)
#pragma unroll
        for (int ct = 0; ct < 4; ++ct)
#pragma unroll
            for (int j = 0; j < 4; ++j) {
                const int r = row0 + wr0 + rt * 16 + g * 4 + j;
                if (r < NN)
                    out[(size_t)r * 64 + ct * 16 + m] = __float2bfloat16(acc[rt][ct][j]);
            }
}

// ---------------- per-bucket CSR finalize (1024 threads) ----------------
__global__ __launch_bounds__(1024) void bucket_csr(const int2* __restrict__ srcdw,
                                                   const int* __restrict__ bcur,
                                                   int2* __restrict__ rng,
                                                   int2* __restrict__ edges2) {
    __shared__ int A[512], B2[512];
    const int tid = threadIdx.x;
    const int b = blockIdx.x;
    const int base = b * CAP;
    const int cnt = bcur[b];                   // relative count
    if (tid < 512) A[tid] = 0;
    __syncthreads();
    for (int e = tid; e < cnt; e += 1024)
        atomicAdd(&A[(srcdw[base + e].x >> 17) & 511], 1);
    __syncthreads();
    const int v = (tid < 512) ? A[tid] : 0;
    int* src = A;
    int* dst = B2;
    for (int d = 1; d < 512; d <<= 1) {
        if (tid < 512) dst[tid] = src[tid] + ((tid >= d) ? src[tid - d] : 0);
        __syncthreads();
        int* t = src; src = dst; dst = t;
    }
    if (tid < 512) {
        const int incl = src[tid];
        const int excl = incl - v;
        const int node = (b << BSHIFT) + tid;
        if (node < NN) rng[node] = make_int2(base + excl, base + incl);
        dst[tid] = excl;
    }
    __syncthreads();
    for (int e = tid; e < cnt; e += 1024) {
        const int2 sw = srcdw[base + e];
        const int dl = (sw.x >> 17) & 511;
        const int pos = atomicAdd(&dst[dl], 1);
        edges2[base + pos] = make_int2(sw.x & 0x1FFFF, sw.y);
    }
}

// ---------------- CSR SpMM: 8 nodes/wave, 8 edges per gather instr ----------------
__global__ __launch_bounds__(256) void spmm_csr(const __hip_bfloat16* __restrict__ feat,
                                                const int2* __restrict__ rng,
                                                const int2* __restrict__ edges2,
                                                const float* __restrict__ b,
                                                float* __restrict__ out) {
    const int nwg = gridDim.x;
    const int q = nwg >> 3, rr = nwg & 7;
    const int xcd = blockIdx.x & 7;
    const int sub = blockIdx.x >> 3;
    const int swz = (xcd < rr ? xcd * (q + 1) : rr * (q + 1) + (xcd - rr) * q) + sub;
    const int w = threadIdx.x >> 6;
    const int lane = threadIdx.x & 63;
    const int n0 = (swz * 4 + w) * NPW;
    const int p = lane >> 3;
    const int f8 = lane & 7;
    const float4 bv0 = *(const float4*)(b + f8 * 8);
    const float4 bv1 = *(const float4*)(b + f8 * 8 + 4);
    const int2 r8 = rng[n0 + f8];
#define FMA8(G, WV)                                            \
    a0 = fmaf(__uint_as_float((G).x << 16), (WV), a0);         \
    a1 = fmaf(__uint_as_float((G).x & 0xffff0000u), (WV), a1); \
    a2 = fmaf(__uint_as_float((G).y << 16), (WV), a2);         \
    a3 = fmaf(__uint_as_float((G).y & 0xffff0000u), (WV), a3); \
    a4 = fmaf(__uint_as_float((G).z << 16), (WV), a4);         \
    a5 = fmaf(__uint_as_float((G).z & 0xffff0000u), (WV), a5); \
    a6 = fmaf(__uint_as_float((G).w << 16), (WV), a6);         \
    a7 = fmaf(__uint_as_float((G).w & 0xffff0000u), (WV), a7);
#define RED(A) A += __shfl_xor(A, 8, 64); A += __shfl_xor(A, 16, 64); A += __shfl_xor(A, 32, 64);
#pragma unroll 1
    for (int nn = 0; nn < NPW; ++nn) {
        const int n = n0 + nn;
        const int beg = __shfl(r8.x, nn, 64);
        const int end = __shfl(r8.y, nn, 64);
        float a0 = 0.f, a1 = 0.f, a2 = 0.f, a3 = 0.f;
        float a4 = 0.f, a5 = 0.f, a6 = 0.f, a7 = 0.f;
        int i = beg;
        for (; i + 15 < end; i += 16) {
            const int2 e0 = edges2[i + p];
            const int2 e1 = edges2[i + 8 + p];
            const uint4 g0 = *(const uint4*)(feat + (size_t)e0.x * 64 + f8 * 8);
            const uint4 g1 = *(const uint4*)(feat + (size_t)e1.x * 64 + f8 * 8);
            const float w0 = __int_as_float(e0.y), w1 = __int_as_float(e1.y);
            FMA8(g0, w0) FMA8(g1, w1)
        }
        for (; i < end; i += 8) {
            const int idx = i + p;
            const int2 e = edges2[idx];
            const float wv = (idx < end) ? __int_as_float(e.y) : 0.f;
            const uint4 g = *(const uint4*)(feat + (size_t)(e.x & 0x1FFFF) * 64 + f8 * 8);
            FMA8(g, wv)
        }
        RED(a0) RED(a1) RED(a2) RED(a3) RED(a4) RED(a5) RED(a6) RED(a7)
        if (p == 0) {
            float4 o0, o1;
            o0.x = fmaxf(a0 + bv0.x, 0.f);
            o0.y = fmaxf(a1 + bv0.y, 0.f);
            o0.z = fmaxf(a2 + bv0.z, 0.f);
            o0.w = fmaxf(a3 + bv0.w, 0.f);
            o1.x = fmaxf(a4 + bv1.x, 0.f);
            o1.y = fmaxf(a5 + bv1.y, 0.f);
            o1.z = fmaxf(a6 + bv1.z, 0.f);
            o1.w = fmaxf(a7 + bv1.w, 0.f);
            *(float4*)(out + (size_t)n * 64 + f8 * 8) = o0;
            *(float4*)(out + (size_t)n * 64 + f8 * 8 + 4) = o1;
        }
    }
#undef FMA8
#undef RED
}

// ============ head: 128 rows x 40 cols per block, register-tiled ============
__global__ __launch_bounds__(256) void head_tile(const float* __restrict__ h2,
                                                 const float* __restrict__ Wl,
                                                 const float* __restrict__ bl,
                                                 float* __restrict__ logits,
                                                 float* __restrict__ logp) {
    __shared__ float Wt[40 * 68];
    __shared__ float Xs[HROWS * 68];
    __shared__ float bs[40];
    const int tid = threadIdx.x;
    const int row0 = blockIdx.x * HROWS;
    for (int i = tid; i < 64 * 40; i += 256) {
        const int k = i / 40, c = i - k * 40;
        Wt[c * 68 + k] = Wl[i];
    }
    if (tid < 40) bs[tid] = bl[tid];
    for (int i = tid; i < HROWS * 16; i += 256) {
        const int r = i >> 4, kq = i & 15;
        const int row = row0 + r;
        float4 v = make_float4(0.f, 0.f, 0.f, 0.f);
        if (row < NN) v = *(const float4*)(h2 + (size_t)row * 64 + kq * 4);
        *(float4*)(&Xs[r * 68 + kq * 4]) = v;
    }
    __syncthreads();
    const int tcol = tid & 3;
    const int trow = tid >> 2;
    float acc[2][10] = {};
    const float* xb0 = &Xs[trow * 68];
    const float* xb1 = &Xs[(trow + 64) * 68];
    const float* wb = &Wt[(tcol * 10) * 68];
    for (int k = 0; k < 64; k += 4) {
        const float4 x0 = *(const float4*)(xb0 + k);
        const float4 x1 = *(const float4*)(xb1 + k);
#pragma unroll
        for (int c = 0; c < 10; ++c) {
            const float4 wv = *(const float4*)(wb + c * 68 + k);
            acc[0][c] = fmaf(x0.x, wv.x, acc[0][c]);
            acc[0][c] = fmaf(x0.y, wv.y, acc[0][c]);
            acc[0][c] = fmaf(x0.z, wv.z, acc[0][c]);
            acc[0][c] = fmaf(x0.w, wv.w, acc[0][c]);
            acc[1][c] = fmaf(x1.x, wv.x, acc[1][c]);
            acc[1][c] = fmaf(x1.y, wv.y, acc[1][c]);
            acc[1][c] = fmaf(x1.z, wv.z, acc[1][c]);
            acc[1][c] = fmaf(x1.w, wv.w, acc[1][c]);
        }
    }
    float bv[10];
#pragma unroll
    for (int c = 0; c < 10; ++c) bv[c] = bs[tcol * 10 + c];
#pragma unroll
    for (int r = 0; r < 2; ++r) {
        const int row = row0 + trow + r * 64;
#pragma unroll
        for (int c = 0; c < 10; ++c) acc[r][c] += bv[c];
        float m = acc[r][0];
#pragma unroll
        for (int c = 1; c < 10; ++c) m = fmaxf(m, acc[r][c]);
        m = fmaxf(m, __shfl_xor(m, 1, 64));
        m = fmaxf(m, __shfl_xor(m, 2, 64));
        float s = 0.f;
#pragma unroll
        for (int c = 0; c < 10; ++c) s += expf(acc[r][c] - m);
        s += __shfl_xor(s, 1, 64);
        s += __shfl_xor(s, 2, 64);
        const float lse = logf(s) + m;
        if (row < NN) {
            float* lg = logits + (size_t)row * 40 + tcol * 10;
            float* lp = logp   + (size_t)row * 40 + tcol * 10;
#pragma unroll
            for (int c = 0; c < 10; c += 2) {
                *(float2*)(lg + c) = make_float2(acc[r][c], acc[r][c + 1]);
                *(float2*)(lp + c) = make_float2(acc[r][c] - lse, acc[r][c + 1] - lse);
            }
        }
    }
}

extern "C" void kernel_launch(void* const* d_in, const int* in_sizes, int n_in,
                              void* d_out, int out_size, void* d_ws, size_t ws_size,
                              hipStream_t stream) {
    const float* x  = (const float*)d_in[0];
    const int*   es = (const int*)  d_in[1];
    const int*   ed = (const int*)  d_in[2];
    const float* ew = (const float*)d_in[3];
    const float* W1 = (const float*)d_in[4];
    const float* b1 = (const float*)d_in[5];
    const float* W2 = (const float*)d_in[6];
    const float* b2 = (const float*)d_in[7];
    const float* Wl = (const float*)d_in[8];
    const float* bl = (const float*)d_in[9];

    float* out    = (float*)d_out;
    float* logp   = out;                          // [N,40]
    float* h1     = logp + (size_t)NN * 40;       // [N,64]
    float* h2     = h1   + (size_t)NN * 64;       // [N,64]
    float* logits = h2   + (size_t)NN * 64;       // [N,40]

    // workspace: NO overlay (ws0 written concurrently with srcdw in the fused kernel)
    char* wsb = (char*)d_ws;
    const size_t regionA = (size_t)NBUCK * CAP * 8;                   // 16.06 MB
    int2* srcdw = (int2*)wsb;                                         // [NBUCK*CAP]
    int2* edges2 = (int2*)(wsb + regionA);                            // [NBUCK*CAP]
    int2* rng    = (int2*)((char*)edges2 + regionA);                  // [NN] 800 KB
    int*  bcur   = (int*)((char*)rng + (size_t)NN * 8);               // [NBUCK]
    __hip_bfloat16* ws0 = (__hip_bfloat16*)((char*)bcur + 4096);      // [N,64] bf16 12.8 MB

    const int gemmGrid = (NN + 127) / 128;        // 782
    const int spmmGrid = NN / (4 * NPW);          // 3125

    // ---- [gemm1 ∥ CSR binning] then per-bucket finalize ----
    hipMemsetAsync(bcur, 0, (size_t)NBUCK * 4, stream);
    gemm1_bin<<<G1GRID + BINGRID, 256, 0, stream>>>(x, W1, ws0, es, ed, ew, bcur, srcdw);
    bucket_csr<<<NBUCK, 1024, 0, stream>>>(srcdw, bcur, rng, edges2);

    // ---- layer 1 aggregate ----
    spmm_csr<<<spmmGrid, 256, 0, stream>>>(ws0, rng, edges2, b1, h1);

    // ---- layer 2 ----
    gemm2_mfma<<<gemmGrid, 256, 0, stream>>>(h1, W2, ws0);
    spmm_csr<<<spmmGrid, 256, 0, stream>>>(ws0, rng, edges2, b2, h2);

    // ---- head ----
    head_tile<<<(NN + HROWS - 1) / HROWS, 256, 0, stream>>>(h2, Wl, bl, logits, logp);
}